// Round 15
// baseline (687.358 us; speedup 1.0000x reference)
//
#include <hip/hip_runtime.h>
#include <cmath>
#include <stdint.h>

typedef unsigned long long u64;
typedef unsigned __int128 u128;

#define EPSF 1e-6f

// ---------------- workspace layout ----------------
#define OFF_RAW 0L            // 7092 raw constants (scaled, f32) -> pad 7168
#define OFF_S   7168L         // 1746 symmetrized S tables (pad to 1792)
#define OFF_G   8960L         // 64 species * 28032 full G tables
#define GSP_SZ  28032L
#define OFF_SN  (OFF_G + 64L*GSP_SZ)   // s_norm [10000][32]
#define OFF_VN  (OFF_SN + 320000L)     // v_norm [10000][32][3]
#define FLOAT_END (OFF_VN + 960000L)   // = 3083008 floats
#define OFF_RAD (FLOAT_END + 262144L)  // [160000][224] f32 = 143.4MB
#define RAD_REQ_BYTES ((size_t)(OFF_RAD + 35840000L) * 4)

#define IOFF_DEG   0
#define IOFF_OFFS  10000
#define IOFF_CUR   20001
#define IOFF_EL    30001
#define IOFF_SCNT  190001
#define IOFF_SOFF  190065
#define IOFF_SCUR  190130
#define IOFF_NORD  190194
#define IOFF_TRI   200194
#define IOFF_PAIR  200359

// raw-constant sub-offsets (floats, within OFF_RAW)
// cg112:0(45) cg121:45(45) u3_0e:90(2187) u3_1o:2277(4374)
// u2_0e:6651(162) u2_1o:6813(243) u1_0e:7056(9) u1_1o:7065(27)
// G per-species layout: G3_0e [165][32] @0; G3_1o [165][3][32] @5280;
//   G2_0e [45][32] @21120; G2_1o [45][3][32] @22560; G1_0e [9][32] @26880;
//   G1_1o [9][3][32] @27168.  total 28032

// ---------------- PCG64 (numpy) ----------------
__device__ __forceinline__ u128 pcg_mul128() {
  return ((u128)2549297995355413924ULL << 64) | (u128)4865540595714422341ULL;
}
struct Pcg {
  u128 state, inc;
  __device__ __forceinline__ u64 next() {
    state = state * pcg_mul128() + inc;
    u64 hi = (u64)(state >> 64), lo = (u64)state;
    unsigned rot = (unsigned)(hi >> 58);
    u64 x = hi ^ lo;
    return (x >> rot) | (x << ((64u - rot) & 63u));
  }
};
__device__ __forceinline__ double u64_to_dbl(u64 u) {
  return (double)(u >> 11) * (1.0 / 9007199254740992.0);
}
__device__ __forceinline__ unsigned ss_hashmix(unsigned v, unsigned &hc) {
  v ^= hc; hc *= 0x931e8875u; v *= hc; v ^= v >> 16; return v;
}
// randutils/numpy mix: MULT_L*x - MULT_R*y (verified round 4/5 via oracle)
__device__ __forceinline__ unsigned ss_mix(unsigned x, unsigned y) {
  unsigned r = 0xca01f9ddu * x - 0x4973f715u * y; r ^= r >> 16; return r;
}

#define NBUF 8192
#define NBM  8191
#define PERTH 32
#define NDRAW 7092
#define NSEG  222

// =====================================================================
// K0 (parallel): reproduce np.random.default_rng(0) stream + S tables.
// (RNG verified rounds 7-14: jump-ahead active, passed, absmax 0.125)
// =====================================================================
__global__ __launch_bounds__(256) void k_constants(float* __restrict__ wsf, int* __restrict__ wsi)
{
  __shared__ double wi[256], fi[256];
  __shared__ u64 ki[256];
  __shared__ u64 buf[NBUF];
  __shared__ float zv[NBUF];
  __shared__ unsigned char cons[NBUF];
  __shared__ unsigned short jmp[NBUF];
  __shared__ unsigned short heads[NSEG];
  __shared__ u64 sseed[4];
  __shared__ u64 stst[512], enst[512];
  __shared__ double scl[8];
  __shared__ int flag;
  const int tid = threadIdx.x;
  float* raw = wsf + OFF_RAW;

  if (tid == 0) {
    flag = 0;
    unsigned hc = 0x43b0d7e5u;
    unsigned pool[4];
    for (int i = 0; i < 4; i++) pool[i] = ss_hashmix(0u, hc);
    for (int s = 0; s < 4; s++)
      for (int d = 0; d < 4; d++)
        if (s != d) pool[d] = ss_mix(pool[d], ss_hashmix(pool[s], hc));
    unsigned hb = 0x8b51f9ddu;
    u64 sw[4];
    {
      unsigned w8[8];
      for (int i = 0; i < 8; i++) {
        unsigned dv = pool[i & 3];
        dv ^= hb; hb *= 0x58f38dedu; dv *= hb; dv ^= dv >> 16;
        w8[i] = dv;
      }
      for (int k2 = 0; k2 < 4; k2++) sw[k2] = (u64)w8[2*k2] | ((u64)w8[2*k2+1] << 32);
    }
    u128 initstate = ((u128)sw[0] << 64) | (u128)sw[1];
    u128 initseq   = ((u128)sw[2] << 64) | (u128)sw[3];
    u128 inc_ = (initseq << 1) | (u128)1;
    u128 S0 = inc_;
    S0 += initstate;
    S0 = S0 * pcg_mul128() + inc_;
    sseed[0] = (u64)(S0 >> 64);   sseed[1] = (u64)S0;
    sseed[2] = (u64)(inc_ >> 64); sseed[3] = (u64)inc_;
    double p2 = pow(0.3, 2.0), p3 = pow(0.3, 3.0);
    scl[0]=0.2; scl[1]=0.2; scl[2]=p3; scl[3]=p3; scl[4]=p2; scl[5]=p2; scl[6]=0.3; scl[7]=0.3;
    const double m1 = 4503599627370496.0;     // 2^52
    const double ZR = 3.6541528853610087963519472518;
    double dn = ZR, tn = ZR;
    const double vn = 4.92867323399e-3;
    double fv = exp(-0.5 * dn * dn);
    double q = vn / fv;
    ki[0] = (u64)((dn / q) * m1);
    ki[1] = 0;
    wi[0] = q / m1;  wi[255] = dn / m1;
    fi[0] = 1.0;     fi[255] = fv;
    for (int i = 254; i >= 1; i--) {
      dn = sqrt(-2.0 * log(vn / dn + fv));
      ki[i+1] = (u64)((dn / tn) * m1);
      tn = dn;
      fv = exp(-0.5 * dn * dn);
      fi[i] = fv;
      wi[i] = dn / m1;
    }
    int mcnt = 0;
    for (int a = 0; a < 9; a++)
      for (int b = a; b < 9; b++)
        for (int j3 = b; j3 < 9; j3++)
          wsi[IOFF_TRI + (mcnt++)] = a | (b << 4) | (j3 << 8);
    int pcnt = 0;
    for (int a = 0; a < 9; a++)
      for (int b = a; b < 9; b++)
        wsi[IOFF_PAIR + (pcnt++)] = a | (b << 4);
  }
  __syncthreads();

  // parallel uint64 generation via affine jump-ahead
  {
    u128 S0   = ((u128)sseed[0] << 64) | (u128)sseed[1];
    u128 inc_ = ((u128)sseed[2] << 64) | (u128)sseed[3];
    u128 aR = (u128)1, cR = (u128)0;
    u128 aP = pcg_mul128(), cP = inc_;
    unsigned e = (unsigned)tid * PERTH;
    while (e) {
      if (e & 1u) { cR = aP * cR + cP; aR = aP * aR; }
      cP = aP * cP + cP;
      aP = aP * aP;
      e >>= 1;
    }
    Pcg g; g.inc = inc_; g.state = aR * S0 + cR;
    stst[tid*2] = (u64)(g.state >> 64); stst[tid*2+1] = (u64)g.state;
    #pragma unroll 4
    for (int k = 0; k < PERTH; k++) buf[tid*PERTH + k] = g.next();
    enst[tid*2] = (u64)(g.state >> 64); enst[tid*2+1] = (u64)g.state;
  }
  __syncthreads();
  if (tid < 255) {
    if (stst[(tid+1)*2] != enst[tid*2] || stst[(tid+1)*2+1] != enst[tid*2+1])
      atomicOr(&flag, 1);
  }
  if (tid == 0) {
    if (fabs(u64_to_dbl(buf[0]) - 0.6369616873214543) > 1e-12) atomicOr(&flag, 1);
  }
  __syncthreads();
  if (flag && tid == 0) {
    u128 S0   = ((u128)sseed[0] << 64) | (u128)sseed[1];
    u128 inc_ = ((u128)sseed[2] << 64) | (u128)sseed[3];
    Pcg g; g.state = S0; g.inc = inc_;
    for (int k = 0; k < NBUF; k++) buf[k] = g.next();
  }
  __syncthreads();

  // speculative ziggurat draw at every position
  const double ZRd  = 3.6541528853610087963519472518;
  const double ZIRd = 0.27366123732975827203338247596;
  for (int k = 0; k < PERTH; k++) {
    const int p = tid*PERTH + k;
    int pos = p;
    int consumed = 0;
    double z = 0.0;
    u64 r = buf[pos & NBM]; pos++; consumed++;
    for (int guard = 0; guard < 64; guard++) {
      int idx = (int)(r & 0xff);
      r >>= 8;
      int sgn = (int)(r & 1);
      u64 rabs = (r >> 1) & 0x000fffffffffffffULL;
      double x = (double)rabs * wi[idx];
      if (sgn) x = -x;
      if (rabs < ki[idx]) { z = x; break; }
      if (idx == 0) {
        double xx = 0.0, yy = 0.0;
        for (int g2 = 0; g2 < 64; g2++) {
          u64 ua = buf[pos & NBM]; pos++; consumed++;
          u64 ub = buf[pos & NBM]; pos++; consumed++;
          xx = -ZIRd * log1p(-u64_to_dbl(ua));
          yy = -log1p(-u64_to_dbl(ub));
          if (yy + yy > xx * xx) break;
        }
        z = ((rabs >> 8) & 1) ? -(ZRd + xx) : (ZRd + xx);
        break;
      } else {
        u64 u = buf[pos & NBM]; pos++; consumed++;
        if ((fi[idx-1] - fi[idx]) * u64_to_dbl(u) + fi[idx] < exp(-0.5 * x * x)) { z = x; break; }
      }
      r = buf[pos & NBM]; pos++; consumed++;
    }
    zv[p] = (float)z;
    cons[p] = (unsigned char)(consumed > 255 ? 255 : consumed);
  }
  __syncthreads();

  // 32-step jump table
  {
    int pos[PERTH];
    #pragma unroll
    for (int k = 0; k < PERTH; k++) pos[k] = tid*PERTH + k;
    for (int s = 0; s < 32; s++) {
      #pragma unroll
      for (int k = 0; k < PERTH; k++) {
        int np = pos[k] + (int)cons[pos[k]];
        pos[k] = (np > NBM) ? NBM : np;
      }
    }
    #pragma unroll
    for (int k = 0; k < PERTH; k++) jmp[tid*PERTH + k] = (unsigned short)pos[k];
  }
  __syncthreads();

  if (tid == 0) {
    int pos = 0;
    for (int m = 0; m < NSEG; m++) { heads[m] = (unsigned short)pos; pos = (int)jmp[pos]; }
  }
  __syncthreads();

  if (tid < NSEG) {
    int pos = (int)heads[tid];
    const int i0 = tid * 32;
    for (int k = 0; k < 32; k++) {
      const int i = i0 + k;
      if (i >= NDRAW) break;
      double sc;
      if      (i < 90)   sc = scl[0];
      else if (i < 6651) sc = scl[2];
      else if (i < 7056) sc = scl[4];
      else               sc = scl[6];
      raw[i] = (float)((double)zv[pos] * sc);
      int np = pos + (int)cons[pos];
      pos = (np > NBM) ? NBM : np;
    }
  }
  __syncthreads();

  // ---- symmetrized monomial S tables (verified r2<->3) ----
  float* Sb = wsf + OFF_S;
  for (int idx = tid; idx < 495; idx += 256) {
    int m = idx / 3, k2 = idx % 3;
    int tp = wsi[IOFF_TRI + m];
    int a = tp & 15, b = (tp >> 4) & 15, j3 = (tp >> 8) & 15;
    int P[6][3] = {{a,b,j3},{a,j3,b},{b,a,j3},{b,j3,a},{j3,a,b},{j3,b,a}};
    float s = 0.f;
    for (int t = 0; t < 6; t++) {
      bool dup = false;
      for (int u = 0; u < t; u++)
        if (P[u][0]==P[t][0] && P[u][1]==P[t][1] && P[u][2]==P[t][2]) { dup = true; break; }
      if (!dup) s += raw[90 + ((P[t][0]*9 + P[t][1])*9 + P[t][2])*3 + k2];
    }
    Sb[m*3 + k2] = s;
  }
  for (int idx = tid; idx < 990; idx += 256) {
    int m = idx / 6, r6 = idx % 6, k2 = r6 / 3, i = r6 % 3;
    int tp = wsi[IOFF_TRI + m];
    int a = tp & 15, b = (tp >> 4) & 15, j3 = (tp >> 8) & 15;
    int P[6][3] = {{a,b,j3},{a,j3,b},{b,a,j3},{b,j3,a},{j3,a,b},{j3,b,a}};
    float s = 0.f;
    for (int t = 0; t < 6; t++) {
      bool dup = false;
      for (int u = 0; u < t; u++)
        if (P[u][0]==P[t][0] && P[u][1]==P[t][1] && P[u][2]==P[t][2]) { dup = true; break; }
      if (!dup) s += raw[2277 + (((P[t][0]*9 + P[t][1])*9 + P[t][2])*2 + k2)*3 + i];
    }
    Sb[495 + (m*2 + k2)*3 + i] = s;
  }
  for (int idx = tid; idx < 90; idx += 256) {
    int m = idx / 2, k2 = idx % 2;
    int pp = wsi[IOFF_PAIR + m]; int a = pp & 15, b = (pp >> 4) & 15;
    float s = raw[6651 + (a*9 + b)*2 + k2];
    if (a != b) s += raw[6651 + (b*9 + a)*2 + k2];
    Sb[1485 + idx] = s;
  }
  for (int idx = tid; idx < 135; idx += 256) {
    int m = idx / 3, i = idx % 3;
    int pp = wsi[IOFF_PAIR + m]; int a = pp & 15, b = (pp >> 4) & 15;
    float s = raw[6813 + (a*9 + b)*3 + i];
    if (a != b) s += raw[6813 + (b*9 + a)*3 + i];
    Sb[1575 + idx] = s;
  }
  for (int idx = tid; idx < 9;  idx += 256) Sb[1710 + idx] = raw[7056 + idx];
  for (int idx = tid; idx < 27; idx += 256) Sb[1719 + idx] = raw[7065 + idx];
}

// =====================================================================
// K1: full per-species G tables (verified equal to in-loop algebra, r14)
// =====================================================================
__global__ __launch_bounds__(256) void k_gtable(
    const float* __restrict__ stab,
    const float* __restrict__ w30e, const float* __restrict__ w31o,
    const float* __restrict__ w20e, const float* __restrict__ w21o,
    const float* __restrict__ w10e, const float* __restrict__ w11o,
    float* __restrict__ wsf)
{
  const int sp = blockIdx.x, tid = threadIdx.x;
  const float* Sb = wsf + OFF_S;
  float* Gsp = wsf + OFF_G + (long)sp * GSP_SZ;
  __shared__ float st[32];
  __shared__ float wl[320];
  if (tid < 32) st[tid] = stab[sp*32 + tid];
  __syncthreads();
  for (int t = tid; t < 320; t += 256) {
    const float* W; int kc, kcs;
    if (t < 96)       { W = w30e; kc = t;       kcs = 96; }
    else if (t < 160) { W = w31o; kc = t - 96;  kcs = 64; }
    else if (t < 224) { W = w20e; kc = t - 160; kcs = 64; }
    else if (t < 256) { W = w21o; kc = t - 224; kcs = 32; }
    else if (t < 288) { W = w10e; kc = t - 256; kcs = 32; }
    else              { W = w11o; kc = t - 288; kcs = 32; }
    float a = 0.f;
    for (int e = 0; e < 32; e++) a += st[e] * W[e*kcs + kc];
    wl[t] = a;
  }
  __syncthreads();
  for (int idx = tid; idx < 5280; idx += 256) {
    int m = idx >> 5, c = idx & 31;
    float a = 0;
    for (int k = 0; k < 3; k++) a += Sb[m*3 + k] * wl[k*32 + c];
    Gsp[idx] = a;
  }
  for (int idx = tid; idx < 15840; idx += 256) {
    int m = idx / 96, r = idx % 96, i = r >> 5, c = r & 31;
    float a = 0;
    for (int k = 0; k < 2; k++) a += Sb[495 + (m*2 + k)*3 + i] * wl[96 + k*32 + c];
    Gsp[5280 + idx] = a;
  }
  for (int idx = tid; idx < 1440; idx += 256) {
    int m = idx >> 5, c = idx & 31;
    float a = 0;
    for (int k = 0; k < 2; k++) a += Sb[1485 + m*2 + k] * wl[160 + k*32 + c];
    Gsp[21120 + idx] = a;
  }
  for (int idx = tid; idx < 4320; idx += 256) {
    int m = idx / 96, r = idx % 96, i = r >> 5, c = r & 31;
    Gsp[22560 + idx] = Sb[1575 + m*3 + i] * wl[224 + c];
  }
  for (int idx = tid; idx < 288; idx += 256) {
    int a2 = idx >> 5, c = idx & 31;
    Gsp[26880 + idx] = Sb[1710 + a2] * wl[256 + c];
  }
  for (int idx = tid; idx < 864; idx += 256) {
    int a2 = idx / 96, r = idx % 96, i = r >> 5, c = r & 31;
    Gsp[27168 + idx] = Sb[1719 + a2*3 + i] * wl[288 + c];
  }
}

// =====================================================================
// K2: node update
// =====================================================================
__global__ __launch_bounds__(256) void k_nodeupd(
    const float* __restrict__ ns, const float* __restrict__ nv,
    const float* __restrict__ Wu0, const float* __restrict__ Wu1,
    float* __restrict__ wsf)
{
  const int tid = threadIdx.x;
  const int nn = blockIdx.x * 8 + (tid >> 5);
  const int c = tid & 31;
  const float INV = 0.17677669529663687f;
  float s = 0.f;
  for (int e = 0; e < 32; e++) s += ns[nn*32 + e] * Wu0[e*32 + c];
  s *= INV;
  float v0 = 0, v1 = 0, v2 = 0;
  for (int e = 0; e < 32; e++) {
    const float w = Wu1[e*32 + c];
    const float* p = nv + (long)(nn*32 + e)*3;
    v0 += p[0]*w; v1 += p[1]*w; v2 += p[2]*w;
  }
  v0 *= INV; v1 *= INV; v2 *= INV;
  float ss = s*s;
  for (int m = 16; m >= 1; m >>= 1) ss += __shfl_xor(ss, m);
  float sv = v0*v0 + v1*v1 + v2*v2;
  for (int m = 16; m >= 1; m >>= 1) sv += __shfl_xor(sv, m);
  float rs = rsqrtf(ss * (1.f/32.f) + EPSF);
  float rv = rsqrtf(sv * (1.f/96.f) + EPSF);
  wsf[OFF_SN + nn*32 + c] = s * rs;
  float* vp = wsf + OFF_VN + (long)(nn*32 + c)*3;
  vp[0] = v0*rv; vp[1] = v1*rv; vp[2] = v2*rv;
}

// =====================================================================
// K2b: per-edge radial MLP + LayerNorm -> rad[e][224] (register-tiled)
// =====================================================================
#define RB_E 32
__global__ __launch_bounds__(256) void k_radial(
    const float* __restrict__ remb, const float* __restrict__ radW,
    const float* __restrict__ radb, const float* __restrict__ ln_g,
    const float* __restrict__ ln_b, float* __restrict__ wsf)
{
  __shared__ float er[RB_E][33];
  __shared__ __align__(16) float pre[RB_E][224];
  __shared__ float4 lg4[56], lb4[56];
  const int tid = threadIdx.x;
  const long e0 = (long)blockIdx.x * RB_E;

  if (tid < 56) { lg4[tid] = ((const float4*)ln_g)[tid]; lb4[tid] = ((const float4*)ln_b)[tid]; }
  for (int i = tid; i < RB_E*32; i += 256) {
    const int e = i >> 5, q = i & 31;
    er[e][q] = remb[(e0 + e)*32 + q];
  }
  __syncthreads();

  if (tid < 224) {
    const int cg = tid % 56, grp = tid / 56;
    const float4 rb = ((const float4*)radb)[cg];
    float4 acc[8];
    #pragma unroll
    for (int k = 0; k < 8; k++) acc[k] = rb;
    const float4* radW4 = (const float4*)radW;
    for (int q = 0; q < 32; q++) {
      const float4 w = radW4[q*56 + cg];
      #pragma unroll
      for (int k = 0; k < 8; k++) {
        const float ev = er[grp*8 + k][q];
        acc[k].x = fmaf(ev, w.x, acc[k].x);
        acc[k].y = fmaf(ev, w.y, acc[k].y);
        acc[k].z = fmaf(ev, w.z, acc[k].z);
        acc[k].w = fmaf(ev, w.w, acc[k].w);
      }
    }
    #pragma unroll
    for (int k = 0; k < 8; k++)
      ((float4*)&pre[grp*8 + k][0])[cg] = acc[k];
  }
  __syncthreads();

  const int wv = tid >> 6, ln = tid & 63;
  for (int k = 0; k < 8; k++) {
    const int e = wv*8 + k;
    float a0 = 0.f, a1 = 0.f, a2 = 0.f, a3 = 0.f;
    if (ln < 56) {
      const float4 v = ((const float4*)&pre[e][0])[ln];
      a0 = v.x; a1 = v.y; a2 = v.z; a3 = v.w;
    }
    float c1 = a0 + a1 + a2 + a3;
    float c2 = a0*a0 + a1*a1 + a2*a2 + a3*a3;
    for (int m = 32; m >= 1; m >>= 1) { c1 += __shfl_xor(c1, m); c2 += __shfl_xor(c2, m); }
    const float mu = c1 * (1.f/224.f);
    const float rvar = rsqrtf(c2*(1.f/224.f) - mu*mu + EPSF);
    if (ln < 56) {
      const float4 lg = lg4[ln], lb = lb4[ln];
      float4 o;
      o.x = lg.x*(a0-mu)*rvar + lb.x;
      o.y = lg.y*(a1-mu)*rvar + lb.y;
      o.z = lg.z*(a2-mu)*rvar + lb.z;
      o.w = lg.w*(a3-mu)*rvar + lb.w;
      ((float4*)(wsf + OFF_RAD))[(e0 + e)*56 + ln] = o;
    }
  }
}

// =====================================================================
// CSR build
// =====================================================================
__global__ void k_zero(int* __restrict__ wsi) {
  int i = blockIdx.x*256 + threadIdx.x;
  if (i < 10000) { wsi[IOFF_DEG + i] = 0; wsi[IOFF_CUR + i] = 0; }
  if (i < 64)    { wsi[IOFF_SCNT + i] = 0; wsi[IOFF_SCUR + i] = 0; }
}
__global__ void k_hist(const int* __restrict__ recv, const int* __restrict__ spec, int* __restrict__ wsi) {
  int e = blockIdx.x*256 + threadIdx.x;
  if (e < 160000) atomicAdd(&wsi[IOFF_DEG + recv[e]], 1);
  if (e < 10000)  atomicAdd(&wsi[IOFF_SCNT + spec[e]], 1);
}
__global__ __launch_bounds__(1024) void k_scan(int* __restrict__ wsi) {
  __shared__ int part[1024];
  const int tid = threadIdx.x;
  int loc[10];
  int base = tid * 10;
  int s = 0;
  for (int t = 0; t < 10; t++) {
    int idx = base + t;
    loc[t] = s;
    s += (idx < 10000) ? wsi[IOFF_DEG + idx] : 0;
  }
  part[tid] = s;
  __syncthreads();
  for (int d = 1; d < 1024; d <<= 1) {
    int v = (tid >= d) ? part[tid - d] : 0;
    __syncthreads();
    part[tid] += v;
    __syncthreads();
  }
  int exc = (tid > 0) ? part[tid - 1] : 0;
  for (int t = 0; t < 10; t++) {
    int idx = base + t;
    if (idx <= 10000) wsi[IOFF_OFFS + idx] = exc + loc[t];
  }
  if (tid == 0) {
    int a = 0;
    for (int s2 = 0; s2 < 64; s2++) { wsi[IOFF_SOFF + s2] = a; a += wsi[IOFF_SCNT + s2]; }
    wsi[IOFF_SOFF + 64] = a;
  }
}
__global__ void k_fill(const int* __restrict__ recv, const int* __restrict__ spec, int* __restrict__ wsi) {
  int e = blockIdx.x*256 + threadIdx.x;
  if (e < 160000) {
    int r = recv[e];
    int p = atomicAdd(&wsi[IOFF_CUR + r], 1);
    wsi[IOFF_EL + wsi[IOFF_OFFS + r] + p] = e;
  }
  if (e < 10000) {
    int sp = spec[e];
    int p = atomicAdd(&wsi[IOFF_SCUR + sp], 1);
    wsi[IOFF_NORD + wsi[IOFF_SOFF + sp] + p] = e;
  }
}

// =====================================================================
// fast message element (per-edge precontracted A/B in ab[0..24))
// =====================================================================
__device__ __forceinline__ float msg_fast(int slot,
    const float* __restrict__ se, const float* __restrict__ ve,
    const float* __restrict__ sh, const float* __restrict__ ab,
    const float* __restrict__ rd)
{
  const float IS3 = 0.57735026918962576f;
  const float IS5 = 0.44721359549995794f;
  float val; int radidx;
  if (slot < 64) {
    radidx = slot;
    if (slot < 32) val = se[slot];
    else {
      int c = slot - 32;
      val = (ve[c*3+0]*sh[0] + ve[c*3+1]*sh[1] + ve[c*3+2]*sh[2]) * IS3;
    }
  } else if (slot < 352) {
    int q = slot - 64; int row = q / 3; int i = q - row*3;
    radidx = 64 + row;
    if (row < 32) val = ve[row*3 + i];
    else if (row < 64) val = se[row - 32] * sh[i] * IS3;
    else {
      int c = row - 64;
      val = ve[c*3+0]*ab[0+i] + ve[c*3+1]*ab[3+i] + ve[c*3+2]*ab[6+i];
    }
  } else {
    int q = slot - 352; int row = q / 5; int p = q - row*5;
    radidx = 160 + row;
    if (row < 32) val = se[row] * sh[3+p] * IS5;
    else {
      int c = row - 32;
      val = ve[c*3+0]*ab[9+p] + ve[c*3+1]*ab[14+p] + ve[c*3+2]*ab[19+p];
    }
  }
  return val * rd[radidx];
}

// =====================================================================
// K3: fused gather/aggregate + node readout.  template<PRE>.
// Round-15: 16 edges staged per group -> 2 barriers/node (was 8).
// =====================================================================
#define MAXE 16
// edge-phase float offsets
#define SM_RAD 0      // 16*224 = 3584
#define SM_SE  3584   // 16*32  -> 4096
#define SM_VE  4096   // 16*96  -> 5632
#define SM_SHH 5632   // 16*8   -> 5760
#define SM_AB  5760   // 16*24  -> 6144
#define SM_CG  6144   // 90     -> 6234
#define SM_LNG 6240   // 224 (PRE=0 only)
#define SM_LNB 6464   // 224
#define SM_RB  6688   // 224 -> 6912
#define SM_ER  6912   // 16*32 (PRE=0 only) -> 7424
// sym-phase float offsets (edge regions dead by then)
#define SM_X    0     // 288
#define SM_O    288   // 672
#define SM_GRED 960   // 1024  (layout: comp*256 + g*32 + c)
#define SM_SYMS 1984  // 32
#define SM_SYMV 2016  // 96
#define SM_SOUT 2112  // 32
// stable
#define SM_REDB 7424  // 12
#define SM_RF   7436  // 4
#define SMEM_N  7440

template<int PRE>
__global__ __launch_bounds__(256) void k_main(
    const float* __restrict__ node_s, const float* __restrict__ node_v,
    const float* __restrict__ vectors, const float* __restrict__ remb,
    const int* __restrict__ nspec,
    const float* __restrict__ radW, const float* __restrict__ radb,
    const float* __restrict__ ln_g, const float* __restrict__ ln_b,
    const float* __restrict__ Wd0, const float* __restrict__ Wd1, const float* __restrict__ Wd2,
    const float* __restrict__ P0, const float* __restrict__ P1,
    const float* __restrict__ Wsk0, const float* __restrict__ Wsk1,
    const float* __restrict__ Wread,
    const float* __restrict__ wsf, const int* __restrict__ wsi,
    float* __restrict__ out)
{
  const int tid = threadIdx.x;
  const int wv  = tid >> 6;
  const int ln  = tid & 63;
  __shared__ __align__(16) float smem[SMEM_N];
  __shared__ int tri_s[165], pair_s[45];

  const int j  = wsi[IOFF_NORD + blockIdx.x];
  const int sp = nspec[j];
  const int e0 = wsi[IOFF_OFFS + j];
  const int e1 = wsi[IOFF_OFFS + j + 1];

  // ---- block-start staging ----
  if (!PRE) {
    for (int i = tid; i < 224; i += 256) {
      smem[SM_LNG + i] = ln_g[i];
      smem[SM_LNB + i] = ln_b[i];
      smem[SM_RB  + i] = radb[i];
    }
  }
  for (int i = tid; i < 90; i += 256) smem[SM_CG + i] = wsf[OFF_RAW + i];
  for (int i = tid; i < 165; i += 256) tri_s[i] = wsi[IOFF_TRI + i];
  for (int i = tid; i < 45;  i += 256) pair_s[i] = wsi[IOFF_PAIR + i];
  __syncthreads();

  // ---- edge loop: 16 edges per group (4 per wave); 2 barriers/group ----
  float acc0 = 0.f, acc1 = 0.f, acc2 = 0.f;
  for (int t = e0; t < e1; t += MAXE) {
    const int nact = (e1 - t < MAXE) ? (e1 - t) : MAXE;
    #pragma unroll
    for (int k = 0; k < 4; k++) {
      const int s = wv*4 + k;          // slot owned by this wave
      const int eidx = t + s;
      if (eidx < e1) {
        const int e = wsi[IOFF_EL + eidx];
        const int n = e >> 4;
        if (ln < 32) {
          smem[SM_SE + s*32 + ln] = wsf[OFF_SN + (long)n*32 + ln];
          if (!PRE) smem[SM_ER + s*32 + ln] = remb[(long)e*32 + ln];
        } else {
          const int l2 = ln - 32;
          const float* vp = wsf + OFF_VN + (long)(n*32 + l2)*3;
          smem[SM_VE + s*96 + l2*3+0] = vp[0];
          smem[SM_VE + s*96 + l2*3+1] = vp[1];
          smem[SM_VE + s*96 + l2*3+2] = vp[2];
        }
        if (ln == 0) {
          const float* vv = vectors + (long)e*3;
          float vx = vv[0], vy = vv[1], vz = vv[2];
          float nr = sqrtf(vx*vx + vy*vy + vz*vz) + EPSF;
          float rx = vx/nr, ry = vy/nr, rz = vz/nr;
          smem[SM_SHH + s*8 + 0] = 1.7320508075688772f * rx;
          smem[SM_SHH + s*8 + 1] = 1.7320508075688772f * ry;
          smem[SM_SHH + s*8 + 2] = 1.7320508075688772f * rz;
          smem[SM_SHH + s*8 + 3] = 3.872983346207417f * rx*ry;
          smem[SM_SHH + s*8 + 4] = 3.872983346207417f * ry*rz;
          smem[SM_SHH + s*8 + 5] = 1.118033988749895f * (3.f*rz*rz - 1.f);
          smem[SM_SHH + s*8 + 6] = 3.872983346207417f * rx*rz;
          smem[SM_SHH + s*8 + 7] = 1.9364916731037085f * (rx*rx - ry*ry);
        }
        if (PRE) {
          if (ln < 56) {
            const float4 v4 = ((const float4*)(wsf + OFF_RAD))[(long)e*56 + ln];
            ((float4*)&smem[SM_RAD + s*224])[ln] = v4;
          }
        } else {
          float aval[4];
          float c1 = 0.f, c2 = 0.f;
          #pragma unroll
          for (int kk = 0; kk < 4; kk++) {
            const int ch = ln + 64*kk;
            if (ch < 224) {
              float a = smem[SM_RB + ch];
              #pragma unroll 8
              for (int q = 0; q < 32; q++)
                a += smem[SM_ER + s*32 + q] * radW[q*224 + ch];
              aval[kk] = a; c1 += a; c2 += a*a;
            }
          }
          for (int m = 32; m >= 1; m >>= 1) { c1 += __shfl_xor(c1, m); c2 += __shfl_xor(c2, m); }
          const float mu = c1 * (1.f/224.f);
          const float rvar = rsqrtf(c2*(1.f/224.f) - mu*mu + EPSF);
          #pragma unroll
          for (int kk = 0; kk < 4; kk++) {
            const int ch = ln + 64*kk;
            if (ch < 224)
              smem[SM_RAD + s*224 + ch] = smem[SM_LNG + ch]*(aval[kk]-mu)*rvar + smem[SM_LNB + ch];
          }
        }
        // per-edge CG precontraction (same-wave shh visible)
        if (ln < 9) {
          const int i2 = ln / 3, i = ln - i2*3;
          float a = 0.f;
          #pragma unroll
          for (int p = 0; p < 5; p++)
            a += smem[SM_SHH + s*8 + 3 + p] * smem[SM_CG + 45 + i2*15 + p*3 + i];
          smem[SM_AB + s*24 + ln] = a;
        } else if (ln < 24) {
          const int q = ln - 9, i = q / 5, p = q - i*5;
          float a = 0.f;
          #pragma unroll
          for (int j2 = 0; j2 < 3; j2++)
            a += smem[SM_SHH + s*8 + j2] * smem[SM_CG + i*15 + j2*5 + p];
          smem[SM_AB + s*24 + 9 + q] = a;
        }
      }
    }
    __syncthreads();
    for (int w = 0; w < nact; w++) {
      const float* se = &smem[SM_SE + w*32];
      const float* ve = &smem[SM_VE + w*96];
      const float* sh = &smem[SM_SHH + w*8];
      const float* ab = &smem[SM_AB + w*24];
      const float* rd = &smem[SM_RAD + w*224];
      acc0 += msg_fast(tid,       se, ve, sh, ab, rd);
      acc1 += msg_fast(tid + 256, se, ve, sh, ab, rd);
      if (tid < 160) acc2 += msg_fast(tid + 512, se, ve, sh, ab, rd);
    }
    __syncthreads();
  }

  // ---- scale + normnorm o0/o1/o2 ----
  float* redbuf = &smem[SM_REDB];
  float* rf     = &smem[SM_RF];
  acc0 *= 0.25f; acc1 *= 0.25f; acc2 *= 0.25f;
  float g0 = 0, g1 = 0, g2 = 0;
  if (tid < 64) g0 = acc0*acc0; else g1 = acc0*acc0;
  if (tid < 96) g1 += acc1*acc1; else g2 += acc1*acc1;
  if (tid < 160) g2 += acc2*acc2;
  for (int m = 32; m >= 1; m >>= 1) { g0 += __shfl_xor(g0, m); g1 += __shfl_xor(g1, m); g2 += __shfl_xor(g2, m); }
  if ((tid & 63) == 0) { redbuf[wv] = g0; redbuf[4+wv] = g1; redbuf[8+wv] = g2; }
  __syncthreads();
  if (tid == 0) {
    float s0 = redbuf[0]+redbuf[1]+redbuf[2]+redbuf[3];
    float s1 = redbuf[4]+redbuf[5]+redbuf[6]+redbuf[7];
    float s2 = redbuf[8]+redbuf[9]+redbuf[10]+redbuf[11];
    rf[0] = rsqrtf(s0*(1.f/64.f)  + EPSF);
    rf[1] = rsqrtf(s1*(1.f/288.f) + EPSF);
    rf[2] = rsqrtf(s2*(1.f/320.f) + EPSF);
  }
  __syncthreads();
  smem[SM_O + tid]       = acc0 * ((tid < 64) ? rf[0] : rf[1]);
  smem[SM_O + tid + 256] = acc1 * ((tid < 96) ? rf[1] : rf[2]);
  if (tid < 160) smem[SM_O + tid + 512] = acc2 * rf[2];
  __syncthreads();

  // ---- A0/A1/A2 projections + normnorm -> x_sym ----
  const float* o_lds = &smem[SM_O];
  float av1, av2 = 0.f;
  if (tid < 32) {
    float a = 0;
    for (int m = 0; m < 64; m++) a += o_lds[m] * Wd0[m*32 + tid];
    av1 = a * 0.125f;
  } else if (tid < 128) {
    int q = tid - 32, d = q/3, i = q - d*3;
    float a = 0;
    for (int m = 0; m < 96; m++) a += o_lds[64 + m*3 + i] * Wd1[m*32 + d];
    av1 = a * 0.10206207261596575f;
  } else {
    int q = tid - 128, d = q/5, p = q - d*5;
    float a = 0;
    for (int m = 0; m < 64; m++) a += o_lds[352 + m*5 + p] * Wd2[m*32 + d];
    av1 = a * 0.125f;
  }
  if (tid < 32) {
    int q = tid + 128, d = q/5, p = q - d*5;
    float a = 0;
    for (int m = 0; m < 64; m++) a += o_lds[352 + m*5 + p] * Wd2[m*32 + d];
    av2 = a * 0.125f;
  }
  float p0 = (tid < 32) ? av1*av1 : 0.f;
  float p1 = (tid >= 32 && tid < 128) ? av1*av1 : 0.f;
  float p2s = (tid >= 128) ? av1*av1 : 0.f;
  if (tid < 32) p2s += av2*av2;
  for (int m = 32; m >= 1; m >>= 1) { p0 += __shfl_xor(p0, m); p1 += __shfl_xor(p1, m); p2s += __shfl_xor(p2s, m); }
  if ((tid & 63) == 0) { redbuf[wv] = p0; redbuf[4+wv] = p1; redbuf[8+wv] = p2s; }
  __syncthreads();
  if (tid == 0) {
    float s0 = redbuf[0]+redbuf[1]+redbuf[2]+redbuf[3];
    float s1 = redbuf[4]+redbuf[5]+redbuf[6]+redbuf[7];
    float s2 = redbuf[8]+redbuf[9]+redbuf[10]+redbuf[11];
    rf[0] = rsqrtf(s0*(1.f/32.f)  + EPSF);
    rf[1] = rsqrtf(s1*(1.f/96.f)  + EPSF);
    rf[2] = rsqrtf(s2*(1.f/160.f) + EPSF);
  }
  __syncthreads();
  float* x_lds = &smem[SM_X];
  if (tid < 32) x_lds[tid*9 + 0] = av1 * rf[0];
  else if (tid < 128) { int q = tid - 32, d = q/3, i = q - d*3; x_lds[d*9 + 1 + i] = av1 * rf[1]; }
  else { int q = tid - 128, d = q/5, p = q - d*5; x_lds[d*9 + 4 + p] = av1 * rf[2]; }
  if (tid < 32) { int q = tid + 128, d = q/5, p = q - d*5; x_lds[d*9 + 4 + p] = av2 * rf[2]; }
  __syncthreads();

  // ---- symmetric contraction: per-species G tables (L2-hot) ----
  float* gred = &smem[SM_GRED];
  const int c = tid & 31, g = tid >> 5;
  float xr[9];
  for (int t2 = 0; t2 < 9; t2++) xr[t2] = x_lds[c*9 + t2];
  const float* Gsp = wsf + OFF_G + (long)sp * GSP_SZ;

  float sa = 0, va0 = 0, va1 = 0, va2 = 0;
  for (int m = g; m < 165; m += 8) {
    const int tp = tri_s[m];
    const float P = xr[tp & 15] * xr[(tp >> 4) & 15] * xr[(tp >> 8) & 15];
    sa += P * Gsp[m*32 + c];
    const float* g3 = Gsp + 5280 + m*96 + c;
    va0 += P*g3[0]; va1 += P*g3[32]; va2 += P*g3[64];
  }
  for (int m = g; m < 45; m += 8) {
    const int pp = pair_s[m];
    const float P = xr[pp & 15] * xr[(pp >> 4) & 15];
    sa += P * Gsp[21120 + m*32 + c];
    const float* g2p = Gsp + 22560 + m*96 + c;
    va0 += P*g2p[0]; va1 += P*g2p[32]; va2 += P*g2p[64];
  }
  if (g == 0) {
    for (int a = 0; a < 9; a++) {
      const float P = xr[a];
      sa += P * Gsp[26880 + a*32 + c];
      const float* g1p = Gsp + 27168 + a*96 + c;
      va0 += P*g1p[0]; va1 += P*g1p[32]; va2 += P*g1p[64];
    }
  }
  gred[0*256 + g*32 + c] = sa;
  gred[1*256 + g*32 + c] = va0;
  gred[2*256 + g*32 + c] = va1;
  gred[3*256 + g*32 + c] = va2;
  __syncthreads();
  float* syms = &smem[SM_SYMS];
  float* symv = &smem[SM_SYMV];
  float* sout = &smem[SM_SOUT];
  if (tid < 128) {
    int cc = tid & 31, comp = tid >> 5;
    float a = 0;
    for (int gg = 0; gg < 8; gg++) a += gred[comp*256 + gg*32 + cc];
    if (comp == 0) syms[cc] = a; else symv[cc*3 + comp - 1] = a;
  }
  __syncthreads();

  // ---- final projections + skip + readout ----
  const float INV = 0.17677669529663687f;
  if (tid < 32) {
    int d = tid; float ps = 0, sk = 0;
    const float* Wp = Wsk0 + (long)sp * 1024;
    for (int c2 = 0; c2 < 32; c2++) {
      ps += syms[c2] * P0[c2*32 + d];
      sk += node_s[j*32 + c2] * Wp[c2*32 + d];
    }
    float val = (ps + sk) * INV;
    sout[d] = val;
    out[(long)j*129 + d] = val;
  } else if (tid < 128) {
    int q = tid - 32, d = q/3, i = q - d*3;
    float pv = 0, sk = 0;
    const float* Wp = Wsk1 + (long)sp * 1024;
    for (int c2 = 0; c2 < 32; c2++) {
      pv += symv[c2*3 + i] * P1[c2*32 + d];
      sk += node_v[(long)(j*32 + c2)*3 + i] * Wp[c2*32 + d];
    }
    out[(long)j*129 + 32 + q] = (pv + sk) * INV;
  }
  __syncthreads();
  if (tid < 32) {
    float p = sout[tid] * Wread[tid];
    for (int m = 16; m >= 1; m >>= 1) p += __shfl_xor(p, m);
    if (tid == 0) out[(long)j*129 + 128] = p * INV;
  }
}

// =====================================================================
extern "C" void kernel_launch(void* const* d_in, const int* in_sizes, int n_in,
                              void* d_out, int out_size, void* d_ws, size_t ws_size,
                              hipStream_t stream)
{
  const float* node_s  = (const float*)d_in[0];
  const float* node_v  = (const float*)d_in[1];
  const float* vectors = (const float*)d_in[2];
  const float* remb    = (const float*)d_in[3];
  const int*   recv    = (const int*)d_in[4];
  const int*   nspec   = (const int*)d_in[5];
  const float* stab    = (const float*)d_in[6];
  const float* Wu0     = (const float*)d_in[7];
  const float* Wu1     = (const float*)d_in[8];
  const float* radW    = (const float*)d_in[9];
  const float* radb    = (const float*)d_in[10];
  const float* ln_g    = (const float*)d_in[11];
  const float* ln_b    = (const float*)d_in[12];
  const float* Wd0     = (const float*)d_in[13];
  const float* Wd1     = (const float*)d_in[14];
  const float* Wd2     = (const float*)d_in[15];
  const float* w30e    = (const float*)d_in[16];
  const float* w31o    = (const float*)d_in[17];
  const float* w20e    = (const float*)d_in[18];
  const float* w21o    = (const float*)d_in[19];
  const float* w10e    = (const float*)d_in[20];
  const float* w11o    = (const float*)d_in[21];
  const float* P0      = (const float*)d_in[22];
  const float* P1      = (const float*)d_in[23];
  const float* Wsk0    = (const float*)d_in[24];
  const float* Wsk1    = (const float*)d_in[25];
  const float* Wread   = (const float*)d_in[26];
  float* out = (float*)d_out;
  float* wsf = (float*)d_ws;
  int*   wsi = (int*)((char*)d_ws + FLOAT_END * sizeof(float));

  const bool pre = (ws_size >= RAD_REQ_BYTES);

  k_constants<<<1, 256, 0, stream>>>(wsf, wsi);
  k_zero<<<40, 256, 0, stream>>>(wsi);
  k_nodeupd<<<1250, 256, 0, stream>>>(node_s, node_v, Wu0, Wu1, wsf);
  if (pre) k_radial<<<5000, 256, 0, stream>>>(remb, radW, radb, ln_g, ln_b, wsf);
  k_hist<<<625, 256, 0, stream>>>(recv, nspec, wsi);
  k_scan<<<1, 1024, 0, stream>>>(wsi);
  k_fill<<<625, 256, 0, stream>>>(recv, nspec, wsi);
  k_gtable<<<64, 256, 0, stream>>>(stab, w30e, w31o, w20e, w21o, w10e, w11o, wsf);
  if (pre) {
    k_main<1><<<10000, 256, 0, stream>>>(node_s, node_v, vectors, remb, nspec,
                                         radW, radb, ln_g, ln_b, Wd0, Wd1, Wd2,
                                         P0, P1, Wsk0, Wsk1, Wread, wsf, wsi, out);
  } else {
    k_main<0><<<10000, 256, 0, stream>>>(node_s, node_v, vectors, remb, nspec,
                                         radW, radb, ln_g, ln_b, Wd0, Wd1, Wd2,
                                         P0, P1, Wsk0, Wsk1, Wread, wsf, wsi, out);
  }
}

// Round 16
// 632.689 us; speedup vs baseline: 1.0864x; 1.0864x over previous
//
#include <hip/hip_runtime.h>
#include <cmath>
#include <stdint.h>

typedef unsigned long long u64;
typedef unsigned __int128 u128;

#define EPSF 1e-6f

// ---------------- workspace layout ----------------
#define OFF_RAW 0L            // 7092 raw constants (scaled, f32) -> pad 7168
#define OFF_S   7168L         // 1746 symmetrized S tables (pad to 1792)
#define OFF_G   8960L         // 64 species * 28032 (only [0..320) = wl used)
#define GSP_SZ  28032L
#define OFF_SN  (OFF_G + 64L*GSP_SZ)   // s_norm [10000][32]
#define OFF_VN  (OFF_SN + 320000L)     // v_norm [10000][32][3]
#define FLOAT_END (OFF_VN + 960000L)   // = 3083008 floats
#define OFF_RAD (FLOAT_END + 262144L)  // [160000][224] f32 = 143.4MB
#define RAD_REQ_BYTES ((size_t)(OFF_RAD + 35840000L) * 4)

#define IOFF_DEG   0
#define IOFF_OFFS  10000
#define IOFF_CUR   20001
#define IOFF_EL    30001
#define IOFF_SCNT  190001
#define IOFF_SOFF  190065
#define IOFF_SCUR  190130
#define IOFF_NORD  190194
#define IOFF_TRI   200194
#define IOFF_PAIR  200359

// raw-constant sub-offsets (floats, within OFF_RAW)
// cg112:0(45) cg121:45(45) u3_0e:90(2187) u3_1o:2277(4374)
// u2_0e:6651(162) u2_1o:6813(243) u1_0e:7056(9) u1_1o:7065(27)
// S layout (within OFF_S): S3_0e:0(495) S3_1o:495(990) S2_0e:1485(90)
//   S2_1o:1575(135) S1_0e:1710(9) S1_1o:1719(27)   total 1746

// ---------------- PCG64 (numpy) ----------------
__device__ __forceinline__ u128 pcg_mul128() {
  return ((u128)2549297995355413924ULL << 64) | (u128)4865540595714422341ULL;
}
struct Pcg {
  u128 state, inc;
  __device__ __forceinline__ u64 next() {
    state = state * pcg_mul128() + inc;
    u64 hi = (u64)(state >> 64), lo = (u64)state;
    unsigned rot = (unsigned)(hi >> 58);
    u64 x = hi ^ lo;
    return (x >> rot) | (x << ((64u - rot) & 63u));
  }
};
__device__ __forceinline__ double u64_to_dbl(u64 u) {
  return (double)(u >> 11) * (1.0 / 9007199254740992.0);
}
__device__ __forceinline__ unsigned ss_hashmix(unsigned v, unsigned &hc) {
  v ^= hc; hc *= 0x931e8875u; v *= hc; v ^= v >> 16; return v;
}
// randutils/numpy mix: MULT_L*x - MULT_R*y (verified round 4/5 via oracle)
__device__ __forceinline__ unsigned ss_mix(unsigned x, unsigned y) {
  unsigned r = 0xca01f9ddu * x - 0x4973f715u * y; r ^= r >> 16; return r;
}

#define NBUF 8192
#define NBM  8191
#define PERTH 32
#define NDRAW 7092
#define NSEG  222

// =====================================================================
// K0 (parallel): reproduce np.random.default_rng(0) stream + S tables.
// (RNG verified rounds 7-15: jump-ahead active, passed, absmax 0.125)
// =====================================================================
__global__ __launch_bounds__(256) void k_constants(float* __restrict__ wsf, int* __restrict__ wsi)
{
  __shared__ double wi[256], fi[256];
  __shared__ u64 ki[256];
  __shared__ u64 buf[NBUF];
  __shared__ float zv[NBUF];
  __shared__ unsigned char cons[NBUF];
  __shared__ unsigned short jmp[NBUF];
  __shared__ unsigned short heads[NSEG];
  __shared__ u64 sseed[4];
  __shared__ u64 stst[512], enst[512];
  __shared__ double scl[8];
  __shared__ int flag;
  const int tid = threadIdx.x;
  float* raw = wsf + OFF_RAW;

  if (tid == 0) {
    flag = 0;
    unsigned hc = 0x43b0d7e5u;
    unsigned pool[4];
    for (int i = 0; i < 4; i++) pool[i] = ss_hashmix(0u, hc);
    for (int s = 0; s < 4; s++)
      for (int d = 0; d < 4; d++)
        if (s != d) pool[d] = ss_mix(pool[d], ss_hashmix(pool[s], hc));
    unsigned hb = 0x8b51f9ddu;
    u64 sw[4];
    {
      unsigned w8[8];
      for (int i = 0; i < 8; i++) {
        unsigned dv = pool[i & 3];
        dv ^= hb; hb *= 0x58f38dedu; dv *= hb; dv ^= dv >> 16;
        w8[i] = dv;
      }
      for (int k2 = 0; k2 < 4; k2++) sw[k2] = (u64)w8[2*k2] | ((u64)w8[2*k2+1] << 32);
    }
    u128 initstate = ((u128)sw[0] << 64) | (u128)sw[1];
    u128 initseq   = ((u128)sw[2] << 64) | (u128)sw[3];
    u128 inc_ = (initseq << 1) | (u128)1;
    u128 S0 = inc_;
    S0 += initstate;
    S0 = S0 * pcg_mul128() + inc_;
    sseed[0] = (u64)(S0 >> 64);   sseed[1] = (u64)S0;
    sseed[2] = (u64)(inc_ >> 64); sseed[3] = (u64)inc_;
    double p2 = pow(0.3, 2.0), p3 = pow(0.3, 3.0);
    scl[0]=0.2; scl[1]=0.2; scl[2]=p3; scl[3]=p3; scl[4]=p2; scl[5]=p2; scl[6]=0.3; scl[7]=0.3;
    const double m1 = 4503599627370496.0;     // 2^52
    const double ZR = 3.6541528853610087963519472518;
    double dn = ZR, tn = ZR;
    const double vn = 4.92867323399e-3;
    double fv = exp(-0.5 * dn * dn);
    double q = vn / fv;
    ki[0] = (u64)((dn / q) * m1);
    ki[1] = 0;
    wi[0] = q / m1;  wi[255] = dn / m1;
    fi[0] = 1.0;     fi[255] = fv;
    for (int i = 254; i >= 1; i--) {
      dn = sqrt(-2.0 * log(vn / dn + fv));
      ki[i+1] = (u64)((dn / tn) * m1);
      tn = dn;
      fv = exp(-0.5 * dn * dn);
      fi[i] = fv;
      wi[i] = dn / m1;
    }
    int mcnt = 0;
    for (int a = 0; a < 9; a++)
      for (int b = a; b < 9; b++)
        for (int j3 = b; j3 < 9; j3++)
          wsi[IOFF_TRI + (mcnt++)] = a | (b << 4) | (j3 << 8);
    int pcnt = 0;
    for (int a = 0; a < 9; a++)
      for (int b = a; b < 9; b++)
        wsi[IOFF_PAIR + (pcnt++)] = a | (b << 4);
  }
  __syncthreads();

  // parallel uint64 generation via affine jump-ahead
  {
    u128 S0   = ((u128)sseed[0] << 64) | (u128)sseed[1];
    u128 inc_ = ((u128)sseed[2] << 64) | (u128)sseed[3];
    u128 aR = (u128)1, cR = (u128)0;
    u128 aP = pcg_mul128(), cP = inc_;
    unsigned e = (unsigned)tid * PERTH;
    while (e) {
      if (e & 1u) { cR = aP * cR + cP; aR = aP * aR; }
      cP = aP * cP + cP;
      aP = aP * aP;
      e >>= 1;
    }
    Pcg g; g.inc = inc_; g.state = aR * S0 + cR;
    stst[tid*2] = (u64)(g.state >> 64); stst[tid*2+1] = (u64)g.state;
    #pragma unroll 4
    for (int k = 0; k < PERTH; k++) buf[tid*PERTH + k] = g.next();
    enst[tid*2] = (u64)(g.state >> 64); enst[tid*2+1] = (u64)g.state;
  }
  __syncthreads();
  if (tid < 255) {
    if (stst[(tid+1)*2] != enst[tid*2] || stst[(tid+1)*2+1] != enst[tid*2+1])
      atomicOr(&flag, 1);
  }
  if (tid == 0) {
    if (fabs(u64_to_dbl(buf[0]) - 0.6369616873214543) > 1e-12) atomicOr(&flag, 1);
  }
  __syncthreads();
  if (flag && tid == 0) {
    u128 S0   = ((u128)sseed[0] << 64) | (u128)sseed[1];
    u128 inc_ = ((u128)sseed[2] << 64) | (u128)sseed[3];
    Pcg g; g.state = S0; g.inc = inc_;
    for (int k = 0; k < NBUF; k++) buf[k] = g.next();
  }
  __syncthreads();

  // speculative ziggurat draw at every position
  const double ZRd  = 3.6541528853610087963519472518;
  const double ZIRd = 0.27366123732975827203338247596;
  for (int k = 0; k < PERTH; k++) {
    const int p = tid*PERTH + k;
    int pos = p;
    int consumed = 0;
    double z = 0.0;
    u64 r = buf[pos & NBM]; pos++; consumed++;
    for (int guard = 0; guard < 64; guard++) {
      int idx = (int)(r & 0xff);
      r >>= 8;
      int sgn = (int)(r & 1);
      u64 rabs = (r >> 1) & 0x000fffffffffffffULL;
      double x = (double)rabs * wi[idx];
      if (sgn) x = -x;
      if (rabs < ki[idx]) { z = x; break; }
      if (idx == 0) {
        double xx = 0.0, yy = 0.0;
        for (int g2 = 0; g2 < 64; g2++) {
          u64 ua = buf[pos & NBM]; pos++; consumed++;
          u64 ub = buf[pos & NBM]; pos++; consumed++;
          xx = -ZIRd * log1p(-u64_to_dbl(ua));
          yy = -log1p(-u64_to_dbl(ub));
          if (yy + yy > xx * xx) break;
        }
        z = ((rabs >> 8) & 1) ? -(ZRd + xx) : (ZRd + xx);
        break;
      } else {
        u64 u = buf[pos & NBM]; pos++; consumed++;
        if ((fi[idx-1] - fi[idx]) * u64_to_dbl(u) + fi[idx] < exp(-0.5 * x * x)) { z = x; break; }
      }
      r = buf[pos & NBM]; pos++; consumed++;
    }
    zv[p] = (float)z;
    cons[p] = (unsigned char)(consumed > 255 ? 255 : consumed);
  }
  __syncthreads();

  // 32-step jump table
  {
    int pos[PERTH];
    #pragma unroll
    for (int k = 0; k < PERTH; k++) pos[k] = tid*PERTH + k;
    for (int s = 0; s < 32; s++) {
      #pragma unroll
      for (int k = 0; k < PERTH; k++) {
        int np = pos[k] + (int)cons[pos[k]];
        pos[k] = (np > NBM) ? NBM : np;
      }
    }
    #pragma unroll
    for (int k = 0; k < PERTH; k++) jmp[tid*PERTH + k] = (unsigned short)pos[k];
  }
  __syncthreads();

  if (tid == 0) {
    int pos = 0;
    for (int m = 0; m < NSEG; m++) { heads[m] = (unsigned short)pos; pos = (int)jmp[pos]; }
  }
  __syncthreads();

  if (tid < NSEG) {
    int pos = (int)heads[tid];
    const int i0 = tid * 32;
    for (int k = 0; k < 32; k++) {
      const int i = i0 + k;
      if (i >= NDRAW) break;
      double sc;
      if      (i < 90)   sc = scl[0];
      else if (i < 6651) sc = scl[2];
      else if (i < 7056) sc = scl[4];
      else               sc = scl[6];
      raw[i] = (float)((double)zv[pos] * sc);
      int np = pos + (int)cons[pos];
      pos = (np > NBM) ? NBM : np;
    }
  }
  __syncthreads();

  // ---- symmetrized monomial S tables (verified r2<->3, r14) ----
  float* Sb = wsf + OFF_S;
  for (int idx = tid; idx < 495; idx += 256) {
    int m = idx / 3, k2 = idx % 3;
    int tp = wsi[IOFF_TRI + m];
    int a = tp & 15, b = (tp >> 4) & 15, j3 = (tp >> 8) & 15;
    int P[6][3] = {{a,b,j3},{a,j3,b},{b,a,j3},{b,j3,a},{j3,a,b},{j3,b,a}};
    float s = 0.f;
    for (int t = 0; t < 6; t++) {
      bool dup = false;
      for (int u = 0; u < t; u++)
        if (P[u][0]==P[t][0] && P[u][1]==P[t][1] && P[u][2]==P[t][2]) { dup = true; break; }
      if (!dup) s += raw[90 + ((P[t][0]*9 + P[t][1])*9 + P[t][2])*3 + k2];
    }
    Sb[m*3 + k2] = s;
  }
  for (int idx = tid; idx < 990; idx += 256) {
    int m = idx / 6, r6 = idx % 6, k2 = r6 / 3, i = r6 % 3;
    int tp = wsi[IOFF_TRI + m];
    int a = tp & 15, b = (tp >> 4) & 15, j3 = (tp >> 8) & 15;
    int P[6][3] = {{a,b,j3},{a,j3,b},{b,a,j3},{b,j3,a},{j3,a,b},{j3,b,a}};
    float s = 0.f;
    for (int t = 0; t < 6; t++) {
      bool dup = false;
      for (int u = 0; u < t; u++)
        if (P[u][0]==P[t][0] && P[u][1]==P[t][1] && P[u][2]==P[t][2]) { dup = true; break; }
      if (!dup) s += raw[2277 + (((P[t][0]*9 + P[t][1])*9 + P[t][2])*2 + k2)*3 + i];
    }
    Sb[495 + (m*2 + k2)*3 + i] = s;
  }
  for (int idx = tid; idx < 90; idx += 256) {
    int m = idx / 2, k2 = idx % 2;
    int pp = wsi[IOFF_PAIR + m]; int a = pp & 15, b = (pp >> 4) & 15;
    float s = raw[6651 + (a*9 + b)*2 + k2];
    if (a != b) s += raw[6651 + (b*9 + a)*2 + k2];
    Sb[1485 + idx] = s;
  }
  for (int idx = tid; idx < 135; idx += 256) {
    int m = idx / 3, i = idx % 3;
    int pp = wsi[IOFF_PAIR + m]; int a = pp & 15, b = (pp >> 4) & 15;
    float s = raw[6813 + (a*9 + b)*3 + i];
    if (a != b) s += raw[6813 + (b*9 + a)*3 + i];
    Sb[1575 + idx] = s;
  }
  for (int idx = tid; idx < 9;  idx += 256) Sb[1710 + idx] = raw[7056 + idx];
  for (int idx = tid; idx < 27; idx += 256) Sb[1719 + idx] = raw[7065 + idx];
}

// =====================================================================
// K_prep: fused [nodeupd (0..1249) | radial (1250..6249) | hist (6250..6874)]
// zeroing of the int counters is done by hipMemsetAsync before this kernel.
// =====================================================================
#define RB_E 32
__global__ __launch_bounds__(256) void k_prep(
    const float* __restrict__ ns, const float* __restrict__ nv,
    const float* __restrict__ Wu0, const float* __restrict__ Wu1,
    const float* __restrict__ remb, const float* __restrict__ radW,
    const float* __restrict__ radb, const float* __restrict__ ln_g,
    const float* __restrict__ ln_b,
    const int* __restrict__ recv, const int* __restrict__ spec,
    int doRad,
    float* __restrict__ wsf, int* __restrict__ wsi)
{
  __shared__ __align__(16) float shbuf[8672];
  const int tid = threadIdx.x;
  const int bid = blockIdx.x;

  if (bid < 1250) {
    // ---- nodeupd (verified since r2) ----
    const int nn = bid * 8 + (tid >> 5);
    const int c = tid & 31;
    const float INV = 0.17677669529663687f;
    float s = 0.f;
    for (int e = 0; e < 32; e++) s += ns[nn*32 + e] * Wu0[e*32 + c];
    s *= INV;
    float v0 = 0, v1 = 0, v2 = 0;
    for (int e = 0; e < 32; e++) {
      const float w = Wu1[e*32 + c];
      const float* p = nv + (long)(nn*32 + e)*3;
      v0 += p[0]*w; v1 += p[1]*w; v2 += p[2]*w;
    }
    v0 *= INV; v1 *= INV; v2 *= INV;
    float ss = s*s;
    for (int m = 16; m >= 1; m >>= 1) ss += __shfl_xor(ss, m);
    float sv = v0*v0 + v1*v1 + v2*v2;
    for (int m = 16; m >= 1; m >>= 1) sv += __shfl_xor(sv, m);
    float rs = rsqrtf(ss * (1.f/32.f) + EPSF);
    float rv = rsqrtf(sv * (1.f/96.f) + EPSF);
    wsf[OFF_SN + nn*32 + c] = s * rs;
    float* vp = wsf + OFF_VN + (long)(nn*32 + c)*3;
    vp[0] = v0*rv; vp[1] = v1*rv; vp[2] = v2*rv;
  } else if (bid < 6250) {
    // ---- radial (register-tiled, verified r13) ----
    if (!doRad) return;
    float (*er)[33] = (float(*)[33])&shbuf[0];     // 1056 floats
    float* pre = &shbuf[1056];                      // [32][224] = 7168
    float4* lg4 = (float4*)&shbuf[8224];            // 56 float4
    float4* lb4 = (float4*)&shbuf[8448];            // 56 float4
    const long e0 = (long)(bid - 1250) * RB_E;

    if (tid < 56) { lg4[tid] = ((const float4*)ln_g)[tid]; lb4[tid] = ((const float4*)ln_b)[tid]; }
    for (int i = tid; i < RB_E*32; i += 256) {
      const int e = i >> 5, q = i & 31;
      er[e][q] = remb[(e0 + e)*32 + q];
    }
    __syncthreads();

    if (tid < 224) {
      const int cg = tid % 56, grp = tid / 56;
      const float4 rb = ((const float4*)radb)[cg];
      float4 acc[8];
      #pragma unroll
      for (int k = 0; k < 8; k++) acc[k] = rb;
      const float4* radW4 = (const float4*)radW;
      for (int q = 0; q < 32; q++) {
        const float4 w = radW4[q*56 + cg];
        #pragma unroll
        for (int k = 0; k < 8; k++) {
          const float ev = er[grp*8 + k][q];
          acc[k].x = fmaf(ev, w.x, acc[k].x);
          acc[k].y = fmaf(ev, w.y, acc[k].y);
          acc[k].z = fmaf(ev, w.z, acc[k].z);
          acc[k].w = fmaf(ev, w.w, acc[k].w);
        }
      }
      #pragma unroll
      for (int k = 0; k < 8; k++)
        ((float4*)&pre[(grp*8 + k)*224])[cg] = acc[k];
    }
    __syncthreads();

    const int wv = tid >> 6, ln = tid & 63;
    for (int k = 0; k < 8; k++) {
      const int e = wv*8 + k;
      float a0 = 0.f, a1 = 0.f, a2 = 0.f, a3 = 0.f;
      if (ln < 56) {
        const float4 v = ((const float4*)&pre[e*224])[ln];
        a0 = v.x; a1 = v.y; a2 = v.z; a3 = v.w;
      }
      float c1 = a0 + a1 + a2 + a3;
      float c2 = a0*a0 + a1*a1 + a2*a2 + a3*a3;
      for (int m = 32; m >= 1; m >>= 1) { c1 += __shfl_xor(c1, m); c2 += __shfl_xor(c2, m); }
      const float mu = c1 * (1.f/224.f);
      const float rvar = rsqrtf(c2*(1.f/224.f) - mu*mu + EPSF);
      if (ln < 56) {
        const float4 lg = lg4[ln], lb = lb4[ln];
        float4 o;
        o.x = lg.x*(a0-mu)*rvar + lb.x;
        o.y = lg.y*(a1-mu)*rvar + lb.y;
        o.z = lg.z*(a2-mu)*rvar + lb.z;
        o.w = lg.w*(a3-mu)*rvar + lb.w;
        ((float4*)(wsf + OFF_RAD))[(e0 + e)*56 + ln] = o;
      }
    }
  } else {
    // ---- hist (zeroed counters via preceding memset) ----
    const int e = (bid - 6250)*256 + tid;
    if (e < 160000) atomicAdd(&wsi[IOFF_DEG + recv[e]], 1);
    if (e < 10000)  atomicAdd(&wsi[IOFF_SCNT + spec[e]], 1);
  }
}

// =====================================================================
// K_scan (unchanged)
// =====================================================================
__global__ __launch_bounds__(1024) void k_scan(int* __restrict__ wsi) {
  __shared__ int part[1024];
  const int tid = threadIdx.x;
  int loc[10];
  int base = tid * 10;
  int s = 0;
  for (int t = 0; t < 10; t++) {
    int idx = base + t;
    loc[t] = s;
    s += (idx < 10000) ? wsi[IOFF_DEG + idx] : 0;
  }
  part[tid] = s;
  __syncthreads();
  for (int d = 1; d < 1024; d <<= 1) {
    int v = (tid >= d) ? part[tid - d] : 0;
    __syncthreads();
    part[tid] += v;
    __syncthreads();
  }
  int exc = (tid > 0) ? part[tid - 1] : 0;
  for (int t = 0; t < 10; t++) {
    int idx = base + t;
    if (idx <= 10000) wsi[IOFF_OFFS + idx] = exc + loc[t];
  }
  if (tid == 0) {
    int a = 0;
    for (int s2 = 0; s2 < 64; s2++) { wsi[IOFF_SOFF + s2] = a; a += wsi[IOFF_SCNT + s2]; }
    wsi[IOFF_SOFF + 64] = a;
  }
}

// =====================================================================
// K_fillg: fused [fill (0..624) | gtable-wl (625..688)]
// =====================================================================
__global__ __launch_bounds__(256) void k_fillg(
    const int* __restrict__ recv, const int* __restrict__ spec,
    const float* __restrict__ stab,
    const float* __restrict__ w30e, const float* __restrict__ w31o,
    const float* __restrict__ w20e, const float* __restrict__ w21o,
    const float* __restrict__ w10e, const float* __restrict__ w11o,
    float* __restrict__ wsf, int* __restrict__ wsi)
{
  __shared__ float st[32];
  const int tid = threadIdx.x;
  const int bid = blockIdx.x;
  if (bid < 625) {
    const int e = bid*256 + tid;
    if (e < 160000) {
      int r = recv[e];
      int p = atomicAdd(&wsi[IOFF_CUR + r], 1);
      wsi[IOFF_EL + wsi[IOFF_OFFS + r] + p] = e;
    }
    if (e < 10000) {
      int sp = spec[e];
      int p = atomicAdd(&wsi[IOFF_SCUR + sp], 1);
      wsi[IOFF_NORD + wsi[IOFF_SOFF + sp] + p] = e;
    }
  } else {
    const int sp = bid - 625;
    float* Gsp = wsf + OFF_G + (long)sp * GSP_SZ;
    if (tid < 32) st[tid] = stab[sp*32 + tid];
    __syncthreads();
    for (int t = tid; t < 320; t += 256) {
      const float* W; int kc, kcs;
      if (t < 96)       { W = w30e; kc = t;       kcs = 96; }
      else if (t < 160) { W = w31o; kc = t - 96;  kcs = 64; }
      else if (t < 224) { W = w20e; kc = t - 160; kcs = 64; }
      else if (t < 256) { W = w21o; kc = t - 224; kcs = 32; }
      else if (t < 288) { W = w10e; kc = t - 256; kcs = 32; }
      else              { W = w11o; kc = t - 288; kcs = 32; }
      float a = 0.f;
      for (int e = 0; e < 32; e++) a += st[e] * W[e*kcs + kc];
      Gsp[t] = a;
    }
  }
}

// =====================================================================
// fast message element (per-edge precontracted A/B in ab[0..24))
// =====================================================================
__device__ __forceinline__ float msg_fast(int slot,
    const float* __restrict__ se, const float* __restrict__ ve,
    const float* __restrict__ sh, const float* __restrict__ ab,
    const float* __restrict__ rd)
{
  const float IS3 = 0.57735026918962576f;
  const float IS5 = 0.44721359549995794f;
  float val; int radidx;
  if (slot < 64) {
    radidx = slot;
    if (slot < 32) val = se[slot];
    else {
      int c = slot - 32;
      val = (ve[c*3+0]*sh[0] + ve[c*3+1]*sh[1] + ve[c*3+2]*sh[2]) * IS3;
    }
  } else if (slot < 352) {
    int q = slot - 64; int row = q / 3; int i = q - row*3;
    radidx = 64 + row;
    if (row < 32) val = ve[row*3 + i];
    else if (row < 64) val = se[row - 32] * sh[i] * IS3;
    else {
      int c = row - 64;
      val = ve[c*3+0]*ab[0+i] + ve[c*3+1]*ab[3+i] + ve[c*3+2]*ab[6+i];
    }
  } else {
    int q = slot - 352; int row = q / 5; int p = q - row*5;
    radidx = 160 + row;
    if (row < 32) val = se[row] * sh[3+p] * IS5;
    else {
      int c = row - 32;
      val = ve[c*3+0]*ab[9+p] + ve[c*3+1]*ab[14+p] + ve[c*3+2]*ab[19+p];
    }
  }
  return val * rd[radidx];
}

// =====================================================================
// K3: fused gather/aggregate + node readout (round-13 version verbatim:
// 4-edge groups, S-tables staged in LDS, wl weights, conflict-free gred).
// =====================================================================
// edge-phase float offsets
#define SM_RAD 0      // 4*224
#define SM_SE  896    // 4*32
#define SM_VE  1024   // 4*96
#define SM_ER  1408   // 4*32
#define SM_SHH 1536   // 4*8
#define SM_AB  1568   // 4*24
#define SM_LNG 1664   // 224 (PRE=0 only)
#define SM_LNB 1888   // 224 (PRE=0 only)
#define SM_RB  2112   // 224 (PRE=0 only)
#define SM_CG  2336   // 90
// sym-phase float offsets (edge regions dead by then)
#define SM_S    0     // 1746
#define SM_X    1746  // 288
#define SM_O    2034  // 672
#define SM_GRED 2706  // 1024  (layout: comp*256 + g*32 + c, conflict-free)
#define SM_SYMS 3730  // 32
#define SM_SYMV 3762  // 96
#define SM_SOUT 3858  // 32
// stable
#define SM_REDB 3890  // 12
#define SM_RF   3902  // 4
#define SMEM_N  3906

template<int PRE>
__global__ __launch_bounds__(256) void k_main(
    const float* __restrict__ node_s, const float* __restrict__ node_v,
    const float* __restrict__ vectors, const float* __restrict__ remb,
    const int* __restrict__ nspec,
    const float* __restrict__ radW, const float* __restrict__ radb,
    const float* __restrict__ ln_g, const float* __restrict__ ln_b,
    const float* __restrict__ Wd0, const float* __restrict__ Wd1, const float* __restrict__ Wd2,
    const float* __restrict__ P0, const float* __restrict__ P1,
    const float* __restrict__ Wsk0, const float* __restrict__ Wsk1,
    const float* __restrict__ Wread,
    const float* __restrict__ wsf, const int* __restrict__ wsi,
    float* __restrict__ out)
{
  const int tid = threadIdx.x;
  const int wv  = tid >> 6;
  const int ln  = tid & 63;
  __shared__ __align__(16) float smem[SMEM_N];
  __shared__ int tri_s[165], pair_s[45];

  const int j  = wsi[IOFF_NORD + blockIdx.x];
  const int sp = nspec[j];
  const int e0 = wsi[IOFF_OFFS + j];
  const int e1 = wsi[IOFF_OFFS + j + 1];

  // ---- block-start staging ----
  if (!PRE) {
    for (int i = tid; i < 224; i += 256) {
      smem[SM_LNG + i] = ln_g[i];
      smem[SM_LNB + i] = ln_b[i];
      smem[SM_RB  + i] = radb[i];
    }
  }
  for (int i = tid; i < 90; i += 256) smem[SM_CG + i] = wsf[OFF_RAW + i];
  __syncthreads();

  // ---- edge loop: 4 edges per group, one wave each; 2 barriers/group ----
  float acc0 = 0.f, acc1 = 0.f, acc2 = 0.f;
  for (int t = e0; t < e1; t += 4) {
    const int eidx = t + wv;
    const bool act = (eidx < e1);
    if (act) {
      const int e = wsi[IOFF_EL + eidx];
      const int n = e >> 4;
      if (ln < 32) {
        smem[SM_SE + wv*32 + ln] = wsf[OFF_SN + (long)n*32 + ln];
        if (!PRE) smem[SM_ER + wv*32 + ln] = remb[(long)e*32 + ln];
      } else {
        const int l2 = ln - 32;
        const float* vp = wsf + OFF_VN + (long)(n*32 + l2)*3;
        smem[SM_VE + wv*96 + l2*3+0] = vp[0];
        smem[SM_VE + wv*96 + l2*3+1] = vp[1];
        smem[SM_VE + wv*96 + l2*3+2] = vp[2];
      }
      if (ln == 0) {
        const float* vv = vectors + (long)e*3;
        float vx = vv[0], vy = vv[1], vz = vv[2];
        float nr = sqrtf(vx*vx + vy*vy + vz*vz) + EPSF;
        float rx = vx/nr, ry = vy/nr, rz = vz/nr;
        smem[SM_SHH + wv*8 + 0] = 1.7320508075688772f * rx;
        smem[SM_SHH + wv*8 + 1] = 1.7320508075688772f * ry;
        smem[SM_SHH + wv*8 + 2] = 1.7320508075688772f * rz;
        smem[SM_SHH + wv*8 + 3] = 3.872983346207417f * rx*ry;
        smem[SM_SHH + wv*8 + 4] = 3.872983346207417f * ry*rz;
        smem[SM_SHH + wv*8 + 5] = 1.118033988749895f * (3.f*rz*rz - 1.f);
        smem[SM_SHH + wv*8 + 6] = 3.872983346207417f * rx*rz;
        smem[SM_SHH + wv*8 + 7] = 1.9364916731037085f * (rx*rx - ry*ry);
      }
      if (PRE) {
        if (ln < 56) {
          const float4 v4 = ((const float4*)(wsf + OFF_RAD))[(long)e*56 + ln];
          ((float4*)&smem[SM_RAD + wv*224])[ln] = v4;
        }
      } else {
        float aval[4];
        float c1 = 0.f, c2 = 0.f;
        #pragma unroll
        for (int k = 0; k < 4; k++) {
          const int ch = ln + 64*k;
          if (ch < 224) {
            float a = smem[SM_RB + ch];
            #pragma unroll 8
            for (int q = 0; q < 32; q++)
              a += smem[SM_ER + wv*32 + q] * radW[q*224 + ch];
            aval[k] = a; c1 += a; c2 += a*a;
          }
        }
        for (int m = 32; m >= 1; m >>= 1) { c1 += __shfl_xor(c1, m); c2 += __shfl_xor(c2, m); }
        const float mu = c1 * (1.f/224.f);
        const float rvar = rsqrtf(c2*(1.f/224.f) - mu*mu + EPSF);
        #pragma unroll
        for (int k = 0; k < 4; k++) {
          const int ch = ln + 64*k;
          if (ch < 224)
            smem[SM_RAD + wv*224 + ch] = smem[SM_LNG + ch]*(aval[k]-mu)*rvar + smem[SM_LNB + ch];
        }
      }
      // per-edge CG precontraction (reads own-wave shh; same-wave visible)
      if (ln < 9) {
        const int i2 = ln / 3, i = ln - i2*3;
        float a = 0.f;
        #pragma unroll
        for (int p = 0; p < 5; p++)
          a += smem[SM_SHH + wv*8 + 3 + p] * smem[SM_CG + 45 + i2*15 + p*3 + i];
        smem[SM_AB + wv*24 + ln] = a;
      } else if (ln < 24) {
        const int q = ln - 9, i = q / 5, p = q - i*5;
        float a = 0.f;
        #pragma unroll
        for (int j2 = 0; j2 < 3; j2++)
          a += smem[SM_SHH + wv*8 + j2] * smem[SM_CG + i*15 + j2*5 + p];
        smem[SM_AB + wv*24 + 9 + q] = a;
      }
    }
    __syncthreads();
    const int nact = (e1 - t < 4) ? (e1 - t) : 4;
    for (int w = 0; w < nact; w++) {
      const float* se = &smem[SM_SE + w*32];
      const float* ve = &smem[SM_VE + w*96];
      const float* sh = &smem[SM_SHH + w*8];
      const float* ab = &smem[SM_AB + w*24];
      const float* rd = &smem[SM_RAD + w*224];
      acc0 += msg_fast(tid,       se, ve, sh, ab, rd);
      acc1 += msg_fast(tid + 256, se, ve, sh, ab, rd);
      if (tid < 160) acc2 += msg_fast(tid + 512, se, ve, sh, ab, rd);
    }
    __syncthreads();
  }

  // ---- stage S tables + tri/pair (edge regions now dead) ----
  for (int i = tid; i < 1746; i += 256) smem[SM_S + i] = wsf[OFF_S + i];
  for (int i = tid; i < 165; i += 256) tri_s[i] = wsi[IOFF_TRI + i];
  for (int i = tid; i < 45;  i += 256) pair_s[i] = wsi[IOFF_PAIR + i];

  // ---- scale + normnorm o0/o1/o2 ----
  float* redbuf = &smem[SM_REDB];
  float* rf     = &smem[SM_RF];
  acc0 *= 0.25f; acc1 *= 0.25f; acc2 *= 0.25f;
  float g0 = 0, g1 = 0, g2 = 0;
  if (tid < 64) g0 = acc0*acc0; else g1 = acc0*acc0;
  if (tid < 96) g1 += acc1*acc1; else g2 += acc1*acc1;
  if (tid < 160) g2 += acc2*acc2;
  for (int m = 32; m >= 1; m >>= 1) { g0 += __shfl_xor(g0, m); g1 += __shfl_xor(g1, m); g2 += __shfl_xor(g2, m); }
  if ((tid & 63) == 0) { redbuf[wv] = g0; redbuf[4+wv] = g1; redbuf[8+wv] = g2; }
  __syncthreads();
  if (tid == 0) {
    float s0 = redbuf[0]+redbuf[1]+redbuf[2]+redbuf[3];
    float s1 = redbuf[4]+redbuf[5]+redbuf[6]+redbuf[7];
    float s2 = redbuf[8]+redbuf[9]+redbuf[10]+redbuf[11];
    rf[0] = rsqrtf(s0*(1.f/64.f)  + EPSF);
    rf[1] = rsqrtf(s1*(1.f/288.f) + EPSF);
    rf[2] = rsqrtf(s2*(1.f/320.f) + EPSF);
  }
  __syncthreads();
  smem[SM_O + tid]       = acc0 * ((tid < 64) ? rf[0] : rf[1]);
  smem[SM_O + tid + 256] = acc1 * ((tid < 96) ? rf[1] : rf[2]);
  if (tid < 160) smem[SM_O + tid + 512] = acc2 * rf[2];
  __syncthreads();

  // ---- A0/A1/A2 projections + normnorm -> x_sym ----
  const float* o_lds = &smem[SM_O];
  float av1, av2 = 0.f;
  if (tid < 32) {
    float a = 0;
    for (int m = 0; m < 64; m++) a += o_lds[m] * Wd0[m*32 + tid];
    av1 = a * 0.125f;
  } else if (tid < 128) {
    int q = tid - 32, d = q/3, i = q - d*3;
    float a = 0;
    for (int m = 0; m < 96; m++) a += o_lds[64 + m*3 + i] * Wd1[m*32 + d];
    av1 = a * 0.10206207261596575f;
  } else {
    int q = tid - 128, d = q/5, p = q - d*5;
    float a = 0;
    for (int m = 0; m < 64; m++) a += o_lds[352 + m*5 + p] * Wd2[m*32 + d];
    av1 = a * 0.125f;
  }
  if (tid < 32) {
    int q = tid + 128, d = q/5, p = q - d*5;
    float a = 0;
    for (int m = 0; m < 64; m++) a += o_lds[352 + m*5 + p] * Wd2[m*32 + d];
    av2 = a * 0.125f;
  }
  float p0 = (tid < 32) ? av1*av1 : 0.f;
  float p1 = (tid >= 32 && tid < 128) ? av1*av1 : 0.f;
  float p2s = (tid >= 128) ? av1*av1 : 0.f;
  if (tid < 32) p2s += av2*av2;
  for (int m = 32; m >= 1; m >>= 1) { p0 += __shfl_xor(p0, m); p1 += __shfl_xor(p1, m); p2s += __shfl_xor(p2s, m); }
  if ((tid & 63) == 0) { redbuf[wv] = p0; redbuf[4+wv] = p1; redbuf[8+wv] = p2s; }
  __syncthreads();
  if (tid == 0) {
    float s0 = redbuf[0]+redbuf[1]+redbuf[2]+redbuf[3];
    float s1 = redbuf[4]+redbuf[5]+redbuf[6]+redbuf[7];
    float s2 = redbuf[8]+redbuf[9]+redbuf[10]+redbuf[11];
    rf[0] = rsqrtf(s0*(1.f/32.f)  + EPSF);
    rf[1] = rsqrtf(s1*(1.f/96.f)  + EPSF);
    rf[2] = rsqrtf(s2*(1.f/160.f) + EPSF);
  }
  __syncthreads();
  float* x_lds = &smem[SM_X];
  if (tid < 32) x_lds[tid*9 + 0] = av1 * rf[0];
  else if (tid < 128) { int q = tid - 32, d = q/3, i = q - d*3; x_lds[d*9 + 1 + i] = av1 * rf[1]; }
  else { int q = tid - 128, d = q/5, p = q - d*5; x_lds[d*9 + 4 + p] = av1 * rf[2]; }
  if (tid < 32) { int q = tid + 128, d = q/5, p = q - d*5; x_lds[d*9 + 4 + p] = av2 * rf[2]; }
  __syncthreads();

  // ---- symmetric contraction: monomial-S path (r13) ----
  const float* Sb = &smem[SM_S];
  float* gred = &smem[SM_GRED];
  const int c = tid & 31, g = tid >> 5;
  float xr[9];
  for (int t2 = 0; t2 < 9; t2++) xr[t2] = x_lds[c*9 + t2];
  const float* wl = wsf + OFF_G + (long)sp * GSP_SZ;
  const float w30a = wl[c], w30b = wl[32 + c], w30c = wl[64 + c];
  const float w31a = wl[96 + c], w31b = wl[128 + c];
  const float w20a = wl[160 + c], w20b = wl[192 + c];
  const float w21  = wl[224 + c];
  const float w10  = wl[256 + c];
  const float w11  = wl[288 + c];

  float sa = 0, va0 = 0, va1 = 0, va2 = 0;
  for (int m = g; m < 165; m += 8) {
    const int tp = tri_s[m];
    const float P = xr[tp & 15] * xr[(tp >> 4) & 15] * xr[(tp >> 8) & 15];
    sa += P * (Sb[m*3+0]*w30a + Sb[m*3+1]*w30b + Sb[m*3+2]*w30c);
    const float* s1p = &Sb[495 + m*6];
    va0 += P * (s1p[0]*w31a + s1p[3]*w31b);
    va1 += P * (s1p[1]*w31a + s1p[4]*w31b);
    va2 += P * (s1p[2]*w31a + s1p[5]*w31b);
  }
  for (int m = g; m < 45; m += 8) {
    const int pp = pair_s[m];
    const float P = xr[pp & 15] * xr[(pp >> 4) & 15];
    sa += P * (Sb[1485 + m*2+0]*w20a + Sb[1485 + m*2+1]*w20b);
    const float* s1p = &Sb[1575 + m*3];
    va0 += P * s1p[0] * w21;
    va1 += P * s1p[1] * w21;
    va2 += P * s1p[2] * w21;
  }
  if (g == 0) {
    for (int a = 0; a < 9; a++) {
      const float xa = xr[a];
      sa += xa * Sb[1710 + a] * w10;
      va0 += xa * Sb[1719 + a*3 + 0] * w11;
      va1 += xa * Sb[1719 + a*3 + 1] * w11;
      va2 += xa * Sb[1719 + a*3 + 2] * w11;
    }
  }
  gred[0*256 + g*32 + c] = sa;
  gred[1*256 + g*32 + c] = va0;
  gred[2*256 + g*32 + c] = va1;
  gred[3*256 + g*32 + c] = va2;
  __syncthreads();
  float* syms = &smem[SM_SYMS];
  float* symv = &smem[SM_SYMV];
  float* sout = &smem[SM_SOUT];
  if (tid < 128) {
    int cc = tid & 31, comp = tid >> 5;
    float a = 0;
    for (int gg = 0; gg < 8; gg++) a += gred[comp*256 + gg*32 + cc];
    if (comp == 0) syms[cc] = a; else symv[cc*3 + comp - 1] = a;
  }
  __syncthreads();

  // ---- final projections + skip + readout ----
  const float INV = 0.17677669529663687f;
  if (tid < 32) {
    int d = tid; float ps = 0, sk = 0;
    const float* Wp = Wsk0 + (long)sp * 1024;
    for (int c2 = 0; c2 < 32; c2++) {
      ps += syms[c2] * P0[c2*32 + d];
      sk += node_s[j*32 + c2] * Wp[c2*32 + d];
    }
    float val = (ps + sk) * INV;
    sout[d] = val;
    out[(long)j*129 + d] = val;
  } else if (tid < 128) {
    int q = tid - 32, d = q/3, i = q - d*3;
    float pv = 0, sk = 0;
    const float* Wp = Wsk1 + (long)sp * 1024;
    for (int c2 = 0; c2 < 32; c2++) {
      pv += symv[c2*3 + i] * P1[c2*32 + d];
      sk += node_v[(long)(j*32 + c2)*3 + i] * Wp[c2*32 + d];
    }
    out[(long)j*129 + 32 + q] = (pv + sk) * INV;
  }
  __syncthreads();
  if (tid < 32) {
    float p = sout[tid] * Wread[tid];
    for (int m = 16; m >= 1; m >>= 1) p += __shfl_xor(p, m);
    if (tid == 0) out[(long)j*129 + 128] = p * INV;
  }
}

// =====================================================================
extern "C" void kernel_launch(void* const* d_in, const int* in_sizes, int n_in,
                              void* d_out, int out_size, void* d_ws, size_t ws_size,
                              hipStream_t stream)
{
  const float* node_s  = (const float*)d_in[0];
  const float* node_v  = (const float*)d_in[1];
  const float* vectors = (const float*)d_in[2];
  const float* remb    = (const float*)d_in[3];
  const int*   recv    = (const int*)d_in[4];
  const int*   nspec   = (const int*)d_in[5];
  const float* stab    = (const float*)d_in[6];
  const float* Wu0     = (const float*)d_in[7];
  const float* Wu1     = (const float*)d_in[8];
  const float* radW    = (const float*)d_in[9];
  const float* radb    = (const float*)d_in[10];
  const float* ln_g    = (const float*)d_in[11];
  const float* ln_b    = (const float*)d_in[12];
  const float* Wd0     = (const float*)d_in[13];
  const float* Wd1     = (const float*)d_in[14];
  const float* Wd2     = (const float*)d_in[15];
  const float* w30e    = (const float*)d_in[16];
  const float* w31o    = (const float*)d_in[17];
  const float* w20e    = (const float*)d_in[18];
  const float* w21o    = (const float*)d_in[19];
  const float* w10e    = (const float*)d_in[20];
  const float* w11o    = (const float*)d_in[21];
  const float* P0      = (const float*)d_in[22];
  const float* P1      = (const float*)d_in[23];
  const float* Wsk0    = (const float*)d_in[24];
  const float* Wsk1    = (const float*)d_in[25];
  const float* Wread   = (const float*)d_in[26];
  float* out = (float*)d_out;
  float* wsf = (float*)d_ws;
  int*   wsi = (int*)((char*)d_ws + FLOAT_END * sizeof(float));

  const bool pre = (ws_size >= RAD_REQ_BYTES);

  // zero DEG/CUR/SCNT/SCUR counters (covers ints [0, IOFF_NORD))
  hipMemsetAsync(wsi, 0, (size_t)IOFF_NORD * sizeof(int), stream);
  k_constants<<<1, 256, 0, stream>>>(wsf, wsi);
  k_prep<<<6875, 256, 0, stream>>>(node_s, node_v, Wu0, Wu1,
                                   remb, radW, radb, ln_g, ln_b,
                                   recv, nspec, pre ? 1 : 0, wsf, wsi);
  k_scan<<<1, 1024, 0, stream>>>(wsi);
  k_fillg<<<689, 256, 0, stream>>>(recv, nspec, stab,
                                   w30e, w31o, w20e, w21o, w10e, w11o,
                                   wsf, wsi);
  if (pre) {
    k_main<1><<<10000, 256, 0, stream>>>(node_s, node_v, vectors, remb, nspec,
                                         radW, radb, ln_g, ln_b, Wd0, Wd1, Wd2,
                                         P0, P1, Wsk0, Wsk1, Wread, wsf, wsi, out);
  } else {
    k_main<0><<<10000, 256, 0, stream>>>(node_s, node_v, vectors, remb, nspec,
                                         radW, radb, ln_g, ln_b, Wd0, Wd1, Wd2,
                                         P0, P1, Wsk0, Wsk1, Wread, wsf, wsi, out);
  }
}

// Round 17
// 596.907 us; speedup vs baseline: 1.1515x; 1.0599x over previous
//
#include <hip/hip_runtime.h>
#include <cmath>
#include <stdint.h>

typedef unsigned long long u64;
typedef unsigned __int128 u128;

#define EPSF 1e-6f

// ---------------- workspace layout ----------------
#define OFF_RAW 0L            // 7092 raw constants (scaled, f32) -> pad 7168
#define OFF_S   7168L         // 1746 symmetrized S tables (pad to 1792)
#define OFF_G   8960L         // 64 species * 28032 (only [0..320) = wl used)
#define GSP_SZ  28032L
#define OFF_SN  (OFF_G + 64L*GSP_SZ)   // s_norm [10000][32]
#define OFF_VN  (OFF_SN + 320000L)     // v_norm [10000][32][3]
#define FLOAT_END (OFF_VN + 960000L)   // = 3083008 floats
#define OFF_RAD (FLOAT_END + 262144L)  // [160000][224] f32 = 143.4MB
#define RAD_REQ_BYTES ((size_t)(OFF_RAD + 35840000L) * 4)
// RNG table stash: species-0 G region floats [8192, 8192+1544) (wl uses [0,320))
#define OFF_RNG (OFF_G + 8192L)

#define IOFF_DEG   0
#define IOFF_OFFS  10000
#define IOFF_CUR   20001
#define IOFF_EL    30001
#define IOFF_SCNT  190001
#define IOFF_SOFF  190065
#define IOFF_SCUR  190130
#define IOFF_NORD  190194
#define IOFF_TRI   200194
#define IOFF_PAIR  200359

// raw-constant sub-offsets (floats, within OFF_RAW)
// cg112:0(45) cg121:45(45) u3_0e:90(2187) u3_1o:2277(4374)
// u2_0e:6651(162) u2_1o:6813(243) u1_0e:7056(9) u1_1o:7065(27)
// S layout (within OFF_S): S3_0e:0(495) S3_1o:495(990) S2_0e:1485(90)
//   S2_1o:1575(135) S1_0e:1710(9) S1_1o:1719(27)   total 1746

// ---------------- PCG64 (numpy) ----------------
__device__ __forceinline__ u128 pcg_mul128() {
  return ((u128)2549297995355413924ULL << 64) | (u128)4865540595714422341ULL;
}
struct Pcg {
  u128 state, inc;
  __device__ __forceinline__ u64 next() {
    state = state * pcg_mul128() + inc;
    u64 hi = (u64)(state >> 64), lo = (u64)state;
    unsigned rot = (unsigned)(hi >> 58);
    u64 x = hi ^ lo;
    return (x >> rot) | (x << ((64u - rot) & 63u));
  }
};
__device__ __forceinline__ double u64_to_dbl(u64 u) {
  return (double)(u >> 11) * (1.0 / 9007199254740992.0);
}
__device__ __forceinline__ unsigned ss_hashmix(unsigned v, unsigned &hc) {
  v ^= hc; hc *= 0x931e8875u; v *= hc; v ^= v >> 16; return v;
}
// randutils/numpy mix: MULT_L*x - MULT_R*y (verified round 4/5 via oracle)
__device__ __forceinline__ unsigned ss_mix(unsigned x, unsigned y) {
  unsigned r = 0xca01f9ddu * x - 0x4973f715u * y; r ^= r >> 16; return r;
}

#define NBUF 8192
#define NBM  8191
#define PERTH 32
#define NDRAW 7092
#define NSEG  222
#define RB_E 32

// =====================================================================
// K_prep: fused [nodeupd (0..1249) | radial (1250..6249) | hist
// (6250..6874) | RNG part-1 (6875: seed + ziggurat tables, serial,
// hidden under radial)].  Counters zeroed by preceding hipMemsetAsync.
// =====================================================================
__global__ __launch_bounds__(256) void k_prep(
    const float* __restrict__ ns, const float* __restrict__ nv,
    const float* __restrict__ Wu0, const float* __restrict__ Wu1,
    const float* __restrict__ remb, const float* __restrict__ radW,
    const float* __restrict__ radb, const float* __restrict__ ln_g,
    const float* __restrict__ ln_b,
    const int* __restrict__ recv, const int* __restrict__ spec,
    int doRad,
    float* __restrict__ wsf, int* __restrict__ wsi)
{
  __shared__ __align__(16) float shbuf[8672];
  const int tid = threadIdx.x;
  const int bid = blockIdx.x;

  if (bid < 1250) {
    // ---- nodeupd (verified since r2) ----
    const int nn = bid * 8 + (tid >> 5);
    const int c = tid & 31;
    const float INV = 0.17677669529663687f;
    float s = 0.f;
    for (int e = 0; e < 32; e++) s += ns[nn*32 + e] * Wu0[e*32 + c];
    s *= INV;
    float v0 = 0, v1 = 0, v2 = 0;
    for (int e = 0; e < 32; e++) {
      const float w = Wu1[e*32 + c];
      const float* p = nv + (long)(nn*32 + e)*3;
      v0 += p[0]*w; v1 += p[1]*w; v2 += p[2]*w;
    }
    v0 *= INV; v1 *= INV; v2 *= INV;
    float ss = s*s;
    for (int m = 16; m >= 1; m >>= 1) ss += __shfl_xor(ss, m);
    float sv = v0*v0 + v1*v1 + v2*v2;
    for (int m = 16; m >= 1; m >>= 1) sv += __shfl_xor(sv, m);
    float rs = rsqrtf(ss * (1.f/32.f) + EPSF);
    float rv = rsqrtf(sv * (1.f/96.f) + EPSF);
    wsf[OFF_SN + nn*32 + c] = s * rs;
    float* vp = wsf + OFF_VN + (long)(nn*32 + c)*3;
    vp[0] = v0*rv; vp[1] = v1*rv; vp[2] = v2*rv;
  } else if (bid < 6250) {
    // ---- radial (register-tiled, verified r13) ----
    if (!doRad) return;
    float (*er)[33] = (float(*)[33])&shbuf[0];
    float* pre = &shbuf[1056];
    float4* lg4 = (float4*)&shbuf[8224];
    float4* lb4 = (float4*)&shbuf[8448];
    const long e0 = (long)(bid - 1250) * RB_E;

    if (tid < 56) { lg4[tid] = ((const float4*)ln_g)[tid]; lb4[tid] = ((const float4*)ln_b)[tid]; }
    for (int i = tid; i < RB_E*32; i += 256) {
      const int e = i >> 5, q = i & 31;
      er[e][q] = remb[(e0 + e)*32 + q];
    }
    __syncthreads();

    if (tid < 224) {
      const int cg = tid % 56, grp = tid / 56;
      const float4 rb = ((const float4*)radb)[cg];
      float4 acc[8];
      #pragma unroll
      for (int k = 0; k < 8; k++) acc[k] = rb;
      const float4* radW4 = (const float4*)radW;
      for (int q = 0; q < 32; q++) {
        const float4 w = radW4[q*56 + cg];
        #pragma unroll
        for (int k = 0; k < 8; k++) {
          const float ev = er[grp*8 + k][q];
          acc[k].x = fmaf(ev, w.x, acc[k].x);
          acc[k].y = fmaf(ev, w.y, acc[k].y);
          acc[k].z = fmaf(ev, w.z, acc[k].z);
          acc[k].w = fmaf(ev, w.w, acc[k].w);
        }
      }
      #pragma unroll
      for (int k = 0; k < 8; k++)
        ((float4*)&pre[(grp*8 + k)*224])[cg] = acc[k];
    }
    __syncthreads();

    const int wv = tid >> 6, ln = tid & 63;
    for (int k = 0; k < 8; k++) {
      const int e = wv*8 + k;
      float a0 = 0.f, a1 = 0.f, a2 = 0.f, a3 = 0.f;
      if (ln < 56) {
        const float4 v = ((const float4*)&pre[e*224])[ln];
        a0 = v.x; a1 = v.y; a2 = v.z; a3 = v.w;
      }
      float c1 = a0 + a1 + a2 + a3;
      float c2 = a0*a0 + a1*a1 + a2*a2 + a3*a3;
      for (int m = 32; m >= 1; m >>= 1) { c1 += __shfl_xor(c1, m); c2 += __shfl_xor(c2, m); }
      const float mu = c1 * (1.f/224.f);
      const float rvar = rsqrtf(c2*(1.f/224.f) - mu*mu + EPSF);
      if (ln < 56) {
        const float4 lg = lg4[ln], lb = lb4[ln];
        float4 o;
        o.x = lg.x*(a0-mu)*rvar + lb.x;
        o.y = lg.y*(a1-mu)*rvar + lb.y;
        o.z = lg.z*(a2-mu)*rvar + lb.z;
        o.w = lg.w*(a3-mu)*rvar + lb.w;
        ((float4*)(wsf + OFF_RAD))[(e0 + e)*56 + ln] = o;
      }
    }
  } else if (bid < 6875) {
    // ---- hist ----
    const int e = (bid - 6250)*256 + tid;
    if (e < 160000) atomicAdd(&wsi[IOFF_DEG + recv[e]], 1);
    if (e < 10000)  atomicAdd(&wsi[IOFF_SCNT + spec[e]], 1);
  } else {
    // ---- RNG part 1: seed + ziggurat tables (serial tid0; hidden) ----
    if (tid != 0) return;
    double* wiG = (double*)(wsf + OFF_RNG);
    double* fiG = (double*)(wsf + OFF_RNG + 512);
    u64*    kiG = (u64*)   (wsf + OFF_RNG + 1024);
    u64*    ssG = (u64*)   (wsf + OFF_RNG + 1536);
    // SeedSequence(0), pool_size=4, entropy=[0] (verified r4/5 oracle)
    unsigned hc = 0x43b0d7e5u;
    unsigned pool[4];
    for (int i = 0; i < 4; i++) pool[i] = ss_hashmix(0u, hc);
    for (int s = 0; s < 4; s++)
      for (int d = 0; d < 4; d++)
        if (s != d) pool[d] = ss_mix(pool[d], ss_hashmix(pool[s], hc));
    unsigned hb = 0x8b51f9ddu;
    u64 sw[4];
    {
      unsigned w8[8];
      for (int i = 0; i < 8; i++) {
        unsigned dv = pool[i & 3];
        dv ^= hb; hb *= 0x58f38dedu; dv *= hb; dv ^= dv >> 16;
        w8[i] = dv;
      }
      for (int k2 = 0; k2 < 4; k2++) sw[k2] = (u64)w8[2*k2] | ((u64)w8[2*k2+1] << 32);
    }
    u128 initstate = ((u128)sw[0] << 64) | (u128)sw[1];
    u128 initseq   = ((u128)sw[2] << 64) | (u128)sw[3];
    u128 inc_ = (initseq << 1) | (u128)1;
    u128 S0 = inc_;
    S0 += initstate;
    S0 = S0 * pcg_mul128() + inc_;
    ssG[0] = (u64)(S0 >> 64);   ssG[1] = (u64)S0;
    ssG[2] = (u64)(inc_ >> 64); ssG[3] = (u64)inc_;
    // ziggurat tables (identical recursion; values round-trip via f64)
    const double m1 = 4503599627370496.0;     // 2^52
    const double ZR = 3.6541528853610087963519472518;
    double dn = ZR, tn = ZR;
    const double vn = 4.92867323399e-3;
    double fv = exp(-0.5 * dn * dn);
    double q = vn / fv;
    kiG[0] = (u64)((dn / q) * m1);
    kiG[1] = 0;
    wiG[0] = q / m1;  wiG[255] = dn / m1;
    fiG[0] = 1.0;     fiG[255] = fv;
    for (int i = 254; i >= 1; i--) {
      dn = sqrt(-2.0 * log(vn / dn + fv));
      kiG[i+1] = (u64)((dn / tn) * m1);
      tn = dn;
      fv = exp(-0.5 * dn * dn);
      fiG[i] = fv;
      wiG[i] = dn / m1;
    }
    // monomial index tables
    int mcnt = 0;
    for (int a = 0; a < 9; a++)
      for (int b = a; b < 9; b++)
        for (int j3 = b; j3 < 9; j3++)
          wsi[IOFF_TRI + (mcnt++)] = a | (b << 4) | (j3 << 8);
    int pcnt = 0;
    for (int a = 0; a < 9; a++)
      for (int b = a; b < 9; b++)
        wsi[IOFF_PAIR + (pcnt++)] = a | (b << 4);
  }
}

// =====================================================================
// K_mid: block 0 = RNG part 2 (jump-ahead, speculative ziggurat, chain,
// fill raw[7092]); block 1 = CSR scan (256 threads x 40).
// =====================================================================
__global__ __launch_bounds__(256) void k_mid(float* __restrict__ wsf, int* __restrict__ wsi)
{
  __shared__ double wi[256], fi[256];
  __shared__ u64 ki[256];
  __shared__ u64 buf[NBUF];
  __shared__ float zv[NBUF];
  __shared__ unsigned char cons[NBUF];
  __shared__ unsigned short jmp[NBUF];
  __shared__ unsigned short heads[NSEG];
  __shared__ u64 stst[512], enst[512];
  __shared__ double scl[8];
  __shared__ int flag;
  __shared__ int part[256];
  const int tid = threadIdx.x;

  if (blockIdx.x == 1) {
    // ---- CSR scan (10000 -> offsets), 40 items/thread ----
    int loc[40];
    const int base = tid * 40;
    int s = 0;
    for (int t = 0; t < 40; t++) {
      const int idx = base + t;
      loc[t] = s;
      s += (idx < 10000) ? wsi[IOFF_DEG + idx] : 0;
    }
    part[tid] = s;
    __syncthreads();
    for (int d = 1; d < 256; d <<= 1) {
      int v = (tid >= d) ? part[tid - d] : 0;
      __syncthreads();
      part[tid] += v;
      __syncthreads();
    }
    const int exc = (tid > 0) ? part[tid - 1] : 0;
    for (int t = 0; t < 40; t++) {
      const int idx = base + t;
      if (idx <= 10000) wsi[IOFF_OFFS + idx] = exc + loc[t];
    }
    if (tid == 0) {
      int a = 0;
      for (int s2 = 0; s2 < 64; s2++) { wsi[IOFF_SOFF + s2] = a; a += wsi[IOFF_SCNT + s2]; }
      wsi[IOFF_SOFF + 64] = a;
    }
    return;
  }

  // ---- block 0: RNG part 2 (verified jump-ahead path, r7-16) ----
  const double* wiG = (const double*)(wsf + OFF_RNG);
  const double* fiG = (const double*)(wsf + OFF_RNG + 512);
  const u64*    kiG = (const u64*)   (wsf + OFF_RNG + 1024);
  const u64*    ssG = (const u64*)   (wsf + OFF_RNG + 1536);
  float* raw = wsf + OFF_RAW;

  wi[tid] = wiG[tid]; fi[tid] = fiG[tid]; ki[tid] = kiG[tid];
  if (tid == 0) {
    flag = 0;
    double p2 = pow(0.3, 2.0), p3 = pow(0.3, 3.0);
    scl[0]=0.2; scl[1]=0.2; scl[2]=p3; scl[3]=p3; scl[4]=p2; scl[5]=p2; scl[6]=0.3; scl[7]=0.3;
  }
  __syncthreads();

  // parallel uint64 generation via affine jump-ahead
  {
    u128 S0   = ((u128)ssG[0] << 64) | (u128)ssG[1];
    u128 inc_ = ((u128)ssG[2] << 64) | (u128)ssG[3];
    u128 aR = (u128)1, cR = (u128)0;
    u128 aP = pcg_mul128(), cP = inc_;
    unsigned e = (unsigned)tid * PERTH;
    while (e) {
      if (e & 1u) { cR = aP * cR + cP; aR = aP * aR; }
      cP = aP * cP + cP;
      aP = aP * aP;
      e >>= 1;
    }
    Pcg g; g.inc = inc_; g.state = aR * S0 + cR;
    stst[tid*2] = (u64)(g.state >> 64); stst[tid*2+1] = (u64)g.state;
    #pragma unroll 4
    for (int k = 0; k < PERTH; k++) buf[tid*PERTH + k] = g.next();
    enst[tid*2] = (u64)(g.state >> 64); enst[tid*2+1] = (u64)g.state;
  }
  __syncthreads();
  if (tid < 255) {
    if (stst[(tid+1)*2] != enst[tid*2] || stst[(tid+1)*2+1] != enst[tid*2+1])
      atomicOr(&flag, 1);
  }
  if (tid == 0) {
    if (fabs(u64_to_dbl(buf[0]) - 0.6369616873214543) > 1e-12) atomicOr(&flag, 1);
  }
  __syncthreads();
  if (flag && tid == 0) {
    u128 S0   = ((u128)ssG[0] << 64) | (u128)ssG[1];
    u128 inc_ = ((u128)ssG[2] << 64) | (u128)ssG[3];
    Pcg g; g.state = S0; g.inc = inc_;
    for (int k = 0; k < NBUF; k++) buf[k] = g.next();
  }
  __syncthreads();

  // speculative ziggurat draw at every position
  const double ZRd  = 3.6541528853610087963519472518;
  const double ZIRd = 0.27366123732975827203338247596;
  for (int k = 0; k < PERTH; k++) {
    const int p = tid*PERTH + k;
    int pos = p;
    int consumed = 0;
    double z = 0.0;
    u64 r = buf[pos & NBM]; pos++; consumed++;
    for (int guard = 0; guard < 64; guard++) {
      int idx = (int)(r & 0xff);
      r >>= 8;
      int sgn = (int)(r & 1);
      u64 rabs = (r >> 1) & 0x000fffffffffffffULL;
      double x = (double)rabs * wi[idx];
      if (sgn) x = -x;
      if (rabs < ki[idx]) { z = x; break; }
      if (idx == 0) {
        double xx = 0.0, yy = 0.0;
        for (int g2 = 0; g2 < 64; g2++) {
          u64 ua = buf[pos & NBM]; pos++; consumed++;
          u64 ub = buf[pos & NBM]; pos++; consumed++;
          xx = -ZIRd * log1p(-u64_to_dbl(ua));
          yy = -log1p(-u64_to_dbl(ub));
          if (yy + yy > xx * xx) break;
        }
        z = ((rabs >> 8) & 1) ? -(ZRd + xx) : (ZRd + xx);
        break;
      } else {
        u64 u = buf[pos & NBM]; pos++; consumed++;
        if ((fi[idx-1] - fi[idx]) * u64_to_dbl(u) + fi[idx] < exp(-0.5 * x * x)) { z = x; break; }
      }
      r = buf[pos & NBM]; pos++; consumed++;
    }
    zv[p] = (float)z;
    cons[p] = (unsigned char)(consumed > 255 ? 255 : consumed);
  }
  __syncthreads();

  // 32-step jump table
  {
    int pos[PERTH];
    #pragma unroll
    for (int k = 0; k < PERTH; k++) pos[k] = tid*PERTH + k;
    for (int s = 0; s < 32; s++) {
      #pragma unroll
      for (int k = 0; k < PERTH; k++) {
        int np = pos[k] + (int)cons[pos[k]];
        pos[k] = (np > NBM) ? NBM : np;
      }
    }
    #pragma unroll
    for (int k = 0; k < PERTH; k++) jmp[tid*PERTH + k] = (unsigned short)pos[k];
  }
  __syncthreads();

  if (tid == 0) {
    int pos = 0;
    for (int m = 0; m < NSEG; m++) { heads[m] = (unsigned short)pos; pos = (int)jmp[pos]; }
  }
  __syncthreads();

  if (tid < NSEG) {
    int pos = (int)heads[tid];
    const int i0 = tid * 32;
    for (int k = 0; k < 32; k++) {
      const int i = i0 + k;
      if (i >= NDRAW) break;
      double sc;
      if      (i < 90)   sc = scl[0];
      else if (i < 6651) sc = scl[2];
      else if (i < 7056) sc = scl[4];
      else               sc = scl[6];
      raw[i] = (float)((double)zv[pos] * sc);
      int np = pos + (int)cons[pos];
      pos = (np > NBM) ? NBM : np;
    }
  }
}

// =====================================================================
// K_fillg: fused [fill (0..624) | gtable-wl (625..688) | S-tables (689)]
// =====================================================================
__global__ __launch_bounds__(256) void k_fillg(
    const int* __restrict__ recv, const int* __restrict__ spec,
    const float* __restrict__ stab,
    const float* __restrict__ w30e, const float* __restrict__ w31o,
    const float* __restrict__ w20e, const float* __restrict__ w21o,
    const float* __restrict__ w10e, const float* __restrict__ w11o,
    float* __restrict__ wsf, int* __restrict__ wsi)
{
  __shared__ float st[32];
  const int tid = threadIdx.x;
  const int bid = blockIdx.x;
  if (bid < 625) {
    const int e = bid*256 + tid;
    if (e < 160000) {
      int r = recv[e];
      int p = atomicAdd(&wsi[IOFF_CUR + r], 1);
      wsi[IOFF_EL + wsi[IOFF_OFFS + r] + p] = e;
    }
    if (e < 10000) {
      int sp = spec[e];
      int p = atomicAdd(&wsi[IOFF_SCUR + sp], 1);
      wsi[IOFF_NORD + wsi[IOFF_SOFF + sp] + p] = e;
    }
  } else if (bid < 689) {
    const int sp = bid - 625;
    float* Gsp = wsf + OFF_G + (long)sp * GSP_SZ;
    if (tid < 32) st[tid] = stab[sp*32 + tid];
    __syncthreads();
    for (int t = tid; t < 320; t += 256) {
      const float* W; int kc, kcs;
      if (t < 96)       { W = w30e; kc = t;       kcs = 96; }
      else if (t < 160) { W = w31o; kc = t - 96;  kcs = 64; }
      else if (t < 224) { W = w20e; kc = t - 160; kcs = 64; }
      else if (t < 256) { W = w21o; kc = t - 224; kcs = 32; }
      else if (t < 288) { W = w10e; kc = t - 256; kcs = 32; }
      else              { W = w11o; kc = t - 288; kcs = 32; }
      float a = 0.f;
      for (int e = 0; e < 32; e++) a += st[e] * W[e*kcs + kc];
      Gsp[t] = a;
    }
  } else {
    // ---- symmetrized monomial S tables (verified r2<->3, r14) ----
    const float* raw = wsf + OFF_RAW;
    float* Sb = wsf + OFF_S;
    for (int idx = tid; idx < 495; idx += 256) {
      int m = idx / 3, k2 = idx % 3;
      int tp = wsi[IOFF_TRI + m];
      int a = tp & 15, b = (tp >> 4) & 15, j3 = (tp >> 8) & 15;
      int P[6][3] = {{a,b,j3},{a,j3,b},{b,a,j3},{b,j3,a},{j3,a,b},{j3,b,a}};
      float s = 0.f;
      for (int t = 0; t < 6; t++) {
        bool dup = false;
        for (int u = 0; u < t; u++)
          if (P[u][0]==P[t][0] && P[u][1]==P[t][1] && P[u][2]==P[t][2]) { dup = true; break; }
        if (!dup) s += raw[90 + ((P[t][0]*9 + P[t][1])*9 + P[t][2])*3 + k2];
      }
      Sb[m*3 + k2] = s;
    }
    for (int idx = tid; idx < 990; idx += 256) {
      int m = idx / 6, r6 = idx % 6, k2 = r6 / 3, i = r6 % 3;
      int tp = wsi[IOFF_TRI + m];
      int a = tp & 15, b = (tp >> 4) & 15, j3 = (tp >> 8) & 15;
      int P[6][3] = {{a,b,j3},{a,j3,b},{b,a,j3},{b,j3,a},{j3,a,b},{j3,b,a}};
      float s = 0.f;
      for (int t = 0; t < 6; t++) {
        bool dup = false;
        for (int u = 0; u < t; u++)
          if (P[u][0]==P[t][0] && P[u][1]==P[t][1] && P[u][2]==P[t][2]) { dup = true; break; }
        if (!dup) s += raw[2277 + (((P[t][0]*9 + P[t][1])*9 + P[t][2])*2 + k2)*3 + i];
      }
      Sb[495 + (m*2 + k2)*3 + i] = s;
    }
    for (int idx = tid; idx < 90; idx += 256) {
      int m = idx / 2, k2 = idx % 2;
      int pp = wsi[IOFF_PAIR + m]; int a = pp & 15, b = (pp >> 4) & 15;
      float s = raw[6651 + (a*9 + b)*2 + k2];
      if (a != b) s += raw[6651 + (b*9 + a)*2 + k2];
      Sb[1485 + idx] = s;
    }
    for (int idx = tid; idx < 135; idx += 256) {
      int m = idx / 3, i = idx % 3;
      int pp = wsi[IOFF_PAIR + m]; int a = pp & 15, b = (pp >> 4) & 15;
      float s = raw[6813 + (a*9 + b)*3 + i];
      if (a != b) s += raw[6813 + (b*9 + a)*3 + i];
      Sb[1575 + idx] = s;
    }
    for (int idx = tid; idx < 9;  idx += 256) Sb[1710 + idx] = raw[7056 + idx];
    for (int idx = tid; idx < 27; idx += 256) Sb[1719 + idx] = raw[7065 + idx];
  }
}

// =====================================================================
// fast message element (per-edge precontracted A/B in ab[0..24))
// =====================================================================
__device__ __forceinline__ float msg_fast(int slot,
    const float* __restrict__ se, const float* __restrict__ ve,
    const float* __restrict__ sh, const float* __restrict__ ab,
    const float* __restrict__ rd)
{
  const float IS3 = 0.57735026918962576f;
  const float IS5 = 0.44721359549995794f;
  float val; int radidx;
  if (slot < 64) {
    radidx = slot;
    if (slot < 32) val = se[slot];
    else {
      int c = slot - 32;
      val = (ve[c*3+0]*sh[0] + ve[c*3+1]*sh[1] + ve[c*3+2]*sh[2]) * IS3;
    }
  } else if (slot < 352) {
    int q = slot - 64; int row = q / 3; int i = q - row*3;
    radidx = 64 + row;
    if (row < 32) val = ve[row*3 + i];
    else if (row < 64) val = se[row - 32] * sh[i] * IS3;
    else {
      int c = row - 64;
      val = ve[c*3+0]*ab[0+i] + ve[c*3+1]*ab[3+i] + ve[c*3+2]*ab[6+i];
    }
  } else {
    int q = slot - 352; int row = q / 5; int p = q - row*5;
    radidx = 160 + row;
    if (row < 32) val = se[row] * sh[3+p] * IS5;
    else {
      int c = row - 32;
      val = ve[c*3+0]*ab[9+p] + ve[c*3+1]*ab[14+p] + ve[c*3+2]*ab[19+p];
    }
  }
  return val * rd[radidx];
}

// =====================================================================
// K3: fused gather/aggregate + node readout (r13 version verbatim).
// =====================================================================
#define SM_RAD 0      // 4*224
#define SM_SE  896    // 4*32
#define SM_VE  1024   // 4*96
#define SM_ER  1408   // 4*32
#define SM_SHH 1536   // 4*8
#define SM_AB  1568   // 4*24
#define SM_LNG 1664   // 224 (PRE=0 only)
#define SM_LNB 1888   // 224 (PRE=0 only)
#define SM_RB  2112   // 224 (PRE=0 only)
#define SM_CG  2336   // 90
#define SM_S    0     // 1746 (sym phase)
#define SM_X    1746  // 288
#define SM_O    2034  // 672
#define SM_GRED 2706  // 1024
#define SM_SYMS 3730  // 32
#define SM_SYMV 3762  // 96
#define SM_SOUT 3858  // 32
#define SM_REDB 3890  // 12
#define SM_RF   3902  // 4
#define SMEM_N  3906

template<int PRE>
__global__ __launch_bounds__(256) void k_main(
    const float* __restrict__ node_s, const float* __restrict__ node_v,
    const float* __restrict__ vectors, const float* __restrict__ remb,
    const int* __restrict__ nspec,
    const float* __restrict__ radW, const float* __restrict__ radb,
    const float* __restrict__ ln_g, const float* __restrict__ ln_b,
    const float* __restrict__ Wd0, const float* __restrict__ Wd1, const float* __restrict__ Wd2,
    const float* __restrict__ P0, const float* __restrict__ P1,
    const float* __restrict__ Wsk0, const float* __restrict__ Wsk1,
    const float* __restrict__ Wread,
    const float* __restrict__ wsf, const int* __restrict__ wsi,
    float* __restrict__ out)
{
  const int tid = threadIdx.x;
  const int wv  = tid >> 6;
  const int ln  = tid & 63;
  __shared__ __align__(16) float smem[SMEM_N];
  __shared__ int tri_s[165], pair_s[45];

  const int j  = wsi[IOFF_NORD + blockIdx.x];
  const int sp = nspec[j];
  const int e0 = wsi[IOFF_OFFS + j];
  const int e1 = wsi[IOFF_OFFS + j + 1];

  if (!PRE) {
    for (int i = tid; i < 224; i += 256) {
      smem[SM_LNG + i] = ln_g[i];
      smem[SM_LNB + i] = ln_b[i];
      smem[SM_RB  + i] = radb[i];
    }
  }
  for (int i = tid; i < 90; i += 256) smem[SM_CG + i] = wsf[OFF_RAW + i];
  __syncthreads();

  float acc0 = 0.f, acc1 = 0.f, acc2 = 0.f;
  for (int t = e0; t < e1; t += 4) {
    const int eidx = t + wv;
    const bool act = (eidx < e1);
    if (act) {
      const int e = wsi[IOFF_EL + eidx];
      const int n = e >> 4;
      if (ln < 32) {
        smem[SM_SE + wv*32 + ln] = wsf[OFF_SN + (long)n*32 + ln];
        if (!PRE) smem[SM_ER + wv*32 + ln] = remb[(long)e*32 + ln];
      } else {
        const int l2 = ln - 32;
        const float* vp = wsf + OFF_VN + (long)(n*32 + l2)*3;
        smem[SM_VE + wv*96 + l2*3+0] = vp[0];
        smem[SM_VE + wv*96 + l2*3+1] = vp[1];
        smem[SM_VE + wv*96 + l2*3+2] = vp[2];
      }
      if (ln == 0) {
        const float* vv = vectors + (long)e*3;
        float vx = vv[0], vy = vv[1], vz = vv[2];
        float nr = sqrtf(vx*vx + vy*vy + vz*vz) + EPSF;
        float rx = vx/nr, ry = vy/nr, rz = vz/nr;
        smem[SM_SHH + wv*8 + 0] = 1.7320508075688772f * rx;
        smem[SM_SHH + wv*8 + 1] = 1.7320508075688772f * ry;
        smem[SM_SHH + wv*8 + 2] = 1.7320508075688772f * rz;
        smem[SM_SHH + wv*8 + 3] = 3.872983346207417f * rx*ry;
        smem[SM_SHH + wv*8 + 4] = 3.872983346207417f * ry*rz;
        smem[SM_SHH + wv*8 + 5] = 1.118033988749895f * (3.f*rz*rz - 1.f);
        smem[SM_SHH + wv*8 + 6] = 3.872983346207417f * rx*rz;
        smem[SM_SHH + wv*8 + 7] = 1.9364916731037085f * (rx*rx - ry*ry);
      }
      if (PRE) {
        if (ln < 56) {
          const float4 v4 = ((const float4*)(wsf + OFF_RAD))[(long)e*56 + ln];
          ((float4*)&smem[SM_RAD + wv*224])[ln] = v4;
        }
      } else {
        float aval[4];
        float c1 = 0.f, c2 = 0.f;
        #pragma unroll
        for (int k = 0; k < 4; k++) {
          const int ch = ln + 64*k;
          if (ch < 224) {
            float a = smem[SM_RB + ch];
            #pragma unroll 8
            for (int q = 0; q < 32; q++)
              a += smem[SM_ER + wv*32 + q] * radW[q*224 + ch];
            aval[k] = a; c1 += a; c2 += a*a;
          }
        }
        for (int m = 32; m >= 1; m >>= 1) { c1 += __shfl_xor(c1, m); c2 += __shfl_xor(c2, m); }
        const float mu = c1 * (1.f/224.f);
        const float rvar = rsqrtf(c2*(1.f/224.f) - mu*mu + EPSF);
        #pragma unroll
        for (int k = 0; k < 4; k++) {
          const int ch = ln + 64*k;
          if (ch < 224)
            smem[SM_RAD + wv*224 + ch] = smem[SM_LNG + ch]*(aval[k]-mu)*rvar + smem[SM_LNB + ch];
        }
      }
      if (ln < 9) {
        const int i2 = ln / 3, i = ln - i2*3;
        float a = 0.f;
        #pragma unroll
        for (int p = 0; p < 5; p++)
          a += smem[SM_SHH + wv*8 + 3 + p] * smem[SM_CG + 45 + i2*15 + p*3 + i];
        smem[SM_AB + wv*24 + ln] = a;
      } else if (ln < 24) {
        const int q = ln - 9, i = q / 5, p = q - i*5;
        float a = 0.f;
        #pragma unroll
        for (int j2 = 0; j2 < 3; j2++)
          a += smem[SM_SHH + wv*8 + j2] * smem[SM_CG + i*15 + j2*5 + p];
        smem[SM_AB + wv*24 + 9 + q] = a;
      }
    }
    __syncthreads();
    const int nact = (e1 - t < 4) ? (e1 - t) : 4;
    for (int w = 0; w < nact; w++) {
      const float* se = &smem[SM_SE + w*32];
      const float* ve = &smem[SM_VE + w*96];
      const float* sh = &smem[SM_SHH + w*8];
      const float* ab = &smem[SM_AB + w*24];
      const float* rd = &smem[SM_RAD + w*224];
      acc0 += msg_fast(tid,       se, ve, sh, ab, rd);
      acc1 += msg_fast(tid + 256, se, ve, sh, ab, rd);
      if (tid < 160) acc2 += msg_fast(tid + 512, se, ve, sh, ab, rd);
    }
    __syncthreads();
  }

  for (int i = tid; i < 1746; i += 256) smem[SM_S + i] = wsf[OFF_S + i];
  for (int i = tid; i < 165; i += 256) tri_s[i] = wsi[IOFF_TRI + i];
  for (int i = tid; i < 45;  i += 256) pair_s[i] = wsi[IOFF_PAIR + i];

  float* redbuf = &smem[SM_REDB];
  float* rf     = &smem[SM_RF];
  acc0 *= 0.25f; acc1 *= 0.25f; acc2 *= 0.25f;
  float g0 = 0, g1 = 0, g2 = 0;
  if (tid < 64) g0 = acc0*acc0; else g1 = acc0*acc0;
  if (tid < 96) g1 += acc1*acc1; else g2 += acc1*acc1;
  if (tid < 160) g2 += acc2*acc2;
  for (int m = 32; m >= 1; m >>= 1) { g0 += __shfl_xor(g0, m); g1 += __shfl_xor(g1, m); g2 += __shfl_xor(g2, m); }
  if ((tid & 63) == 0) { redbuf[wv] = g0; redbuf[4+wv] = g1; redbuf[8+wv] = g2; }
  __syncthreads();
  if (tid == 0) {
    float s0 = redbuf[0]+redbuf[1]+redbuf[2]+redbuf[3];
    float s1 = redbuf[4]+redbuf[5]+redbuf[6]+redbuf[7];
    float s2 = redbuf[8]+redbuf[9]+redbuf[10]+redbuf[11];
    rf[0] = rsqrtf(s0*(1.f/64.f)  + EPSF);
    rf[1] = rsqrtf(s1*(1.f/288.f) + EPSF);
    rf[2] = rsqrtf(s2*(1.f/320.f) + EPSF);
  }
  __syncthreads();
  smem[SM_O + tid]       = acc0 * ((tid < 64) ? rf[0] : rf[1]);
  smem[SM_O + tid + 256] = acc1 * ((tid < 96) ? rf[1] : rf[2]);
  if (tid < 160) smem[SM_O + tid + 512] = acc2 * rf[2];
  __syncthreads();

  const float* o_lds = &smem[SM_O];
  float av1, av2 = 0.f;
  if (tid < 32) {
    float a = 0;
    for (int m = 0; m < 64; m++) a += o_lds[m] * Wd0[m*32 + tid];
    av1 = a * 0.125f;
  } else if (tid < 128) {
    int q = tid - 32, d = q/3, i = q - d*3;
    float a = 0;
    for (int m = 0; m < 96; m++) a += o_lds[64 + m*3 + i] * Wd1[m*32 + d];
    av1 = a * 0.10206207261596575f;
  } else {
    int q = tid - 128, d = q/5, p = q - d*5;
    float a = 0;
    for (int m = 0; m < 64; m++) a += o_lds[352 + m*5 + p] * Wd2[m*32 + d];
    av1 = a * 0.125f;
  }
  if (tid < 32) {
    int q = tid + 128, d = q/5, p = q - d*5;
    float a = 0;
    for (int m = 0; m < 64; m++) a += o_lds[352 + m*5 + p] * Wd2[m*32 + d];
    av2 = a * 0.125f;
  }
  float p0 = (tid < 32) ? av1*av1 : 0.f;
  float p1 = (tid >= 32 && tid < 128) ? av1*av1 : 0.f;
  float p2s = (tid >= 128) ? av1*av1 : 0.f;
  if (tid < 32) p2s += av2*av2;
  for (int m = 32; m >= 1; m >>= 1) { p0 += __shfl_xor(p0, m); p1 += __shfl_xor(p1, m); p2s += __shfl_xor(p2s, m); }
  if ((tid & 63) == 0) { redbuf[wv] = p0; redbuf[4+wv] = p1; redbuf[8+wv] = p2s; }
  __syncthreads();
  if (tid == 0) {
    float s0 = redbuf[0]+redbuf[1]+redbuf[2]+redbuf[3];
    float s1 = redbuf[4]+redbuf[5]+redbuf[6]+redbuf[7];
    float s2 = redbuf[8]+redbuf[9]+redbuf[10]+redbuf[11];
    rf[0] = rsqrtf(s0*(1.f/32.f)  + EPSF);
    rf[1] = rsqrtf(s1*(1.f/96.f)  + EPSF);
    rf[2] = rsqrtf(s2*(1.f/160.f) + EPSF);
  }
  __syncthreads();
  float* x_lds = &smem[SM_X];
  if (tid < 32) x_lds[tid*9 + 0] = av1 * rf[0];
  else if (tid < 128) { int q = tid - 32, d = q/3, i = q - d*3; x_lds[d*9 + 1 + i] = av1 * rf[1]; }
  else { int q = tid - 128, d = q/5, p = q - d*5; x_lds[d*9 + 4 + p] = av1 * rf[2]; }
  if (tid < 32) { int q = tid + 128, d = q/5, p = q - d*5; x_lds[d*9 + 4 + p] = av2 * rf[2]; }
  __syncthreads();

  const float* Sb = &smem[SM_S];
  float* gred = &smem[SM_GRED];
  const int c = tid & 31, g = tid >> 5;
  float xr[9];
  for (int t2 = 0; t2 < 9; t2++) xr[t2] = x_lds[c*9 + t2];
  const float* wl = wsf + OFF_G + (long)sp * GSP_SZ;
  const float w30a = wl[c], w30b = wl[32 + c], w30c = wl[64 + c];
  const float w31a = wl[96 + c], w31b = wl[128 + c];
  const float w20a = wl[160 + c], w20b = wl[192 + c];
  const float w21  = wl[224 + c];
  const float w10  = wl[256 + c];
  const float w11  = wl[288 + c];

  float sa = 0, va0 = 0, va1 = 0, va2 = 0;
  for (int m = g; m < 165; m += 8) {
    const int tp = tri_s[m];
    const float P = xr[tp & 15] * xr[(tp >> 4) & 15] * xr[(tp >> 8) & 15];
    sa += P * (Sb[m*3+0]*w30a + Sb[m*3+1]*w30b + Sb[m*3+2]*w30c);
    const float* s1p = &Sb[495 + m*6];
    va0 += P * (s1p[0]*w31a + s1p[3]*w31b);
    va1 += P * (s1p[1]*w31a + s1p[4]*w31b);
    va2 += P * (s1p[2]*w31a + s1p[5]*w31b);
  }
  for (int m = g; m < 45; m += 8) {
    const int pp = pair_s[m];
    const float P = xr[pp & 15] * xr[(pp >> 4) & 15];
    sa += P * (Sb[1485 + m*2+0]*w20a + Sb[1485 + m*2+1]*w20b);
    const float* s1p = &Sb[1575 + m*3];
    va0 += P * s1p[0] * w21;
    va1 += P * s1p[1] * w21;
    va2 += P * s1p[2] * w21;
  }
  if (g == 0) {
    for (int a = 0; a < 9; a++) {
      const float xa = xr[a];
      sa += xa * Sb[1710 + a] * w10;
      va0 += xa * Sb[1719 + a*3 + 0] * w11;
      va1 += xa * Sb[1719 + a*3 + 1] * w11;
      va2 += xa * Sb[1719 + a*3 + 2] * w11;
    }
  }
  gred[0*256 + g*32 + c] = sa;
  gred[1*256 + g*32 + c] = va0;
  gred[2*256 + g*32 + c] = va1;
  gred[3*256 + g*32 + c] = va2;
  __syncthreads();
  float* syms = &smem[SM_SYMS];
  float* symv = &smem[SM_SYMV];
  float* sout = &smem[SM_SOUT];
  if (tid < 128) {
    int cc = tid & 31, comp = tid >> 5;
    float a = 0;
    for (int gg = 0; gg < 8; gg++) a += gred[comp*256 + gg*32 + cc];
    if (comp == 0) syms[cc] = a; else symv[cc*3 + comp - 1] = a;
  }
  __syncthreads();

  const float INV = 0.17677669529663687f;
  if (tid < 32) {
    int d = tid; float ps = 0, sk = 0;
    const float* Wp = Wsk0 + (long)sp * 1024;
    for (int c2 = 0; c2 < 32; c2++) {
      ps += syms[c2] * P0[c2*32 + d];
      sk += node_s[j*32 + c2] * Wp[c2*32 + d];
    }
    float val = (ps + sk) * INV;
    sout[d] = val;
    out[(long)j*129 + d] = val;
  } else if (tid < 128) {
    int q = tid - 32, d = q/3, i = q - d*3;
    float pv = 0, sk = 0;
    const float* Wp = Wsk1 + (long)sp * 1024;
    for (int c2 = 0; c2 < 32; c2++) {
      pv += symv[c2*3 + i] * P1[c2*32 + d];
      sk += node_v[(long)(j*32 + c2)*3 + i] * Wp[c2*32 + d];
    }
    out[(long)j*129 + 32 + q] = (pv + sk) * INV;
  }
  __syncthreads();
  if (tid < 32) {
    float p = sout[tid] * Wread[tid];
    for (int m = 16; m >= 1; m >>= 1) p += __shfl_xor(p, m);
    if (tid == 0) out[(long)j*129 + 128] = p * INV;
  }
}

// =====================================================================
extern "C" void kernel_launch(void* const* d_in, const int* in_sizes, int n_in,
                              void* d_out, int out_size, void* d_ws, size_t ws_size,
                              hipStream_t stream)
{
  const float* node_s  = (const float*)d_in[0];
  const float* node_v  = (const float*)d_in[1];
  const float* vectors = (const float*)d_in[2];
  const float* remb    = (const float*)d_in[3];
  const int*   recv    = (const int*)d_in[4];
  const int*   nspec   = (const int*)d_in[5];
  const float* stab    = (const float*)d_in[6];
  const float* Wu0     = (const float*)d_in[7];
  const float* Wu1     = (const float*)d_in[8];
  const float* radW    = (const float*)d_in[9];
  const float* radb    = (const float*)d_in[10];
  const float* ln_g    = (const float*)d_in[11];
  const float* ln_b    = (const float*)d_in[12];
  const float* Wd0     = (const float*)d_in[13];
  const float* Wd1     = (const float*)d_in[14];
  const float* Wd2     = (const float*)d_in[15];
  const float* w30e    = (const float*)d_in[16];
  const float* w31o    = (const float*)d_in[17];
  const float* w20e    = (const float*)d_in[18];
  const float* w21o    = (const float*)d_in[19];
  const float* w10e    = (const float*)d_in[20];
  const float* w11o    = (const float*)d_in[21];
  const float* P0      = (const float*)d_in[22];
  const float* P1      = (const float*)d_in[23];
  const float* Wsk0    = (const float*)d_in[24];
  const float* Wsk1    = (const float*)d_in[25];
  const float* Wread   = (const float*)d_in[26];
  float* out = (float*)d_out;
  float* wsf = (float*)d_ws;
  int*   wsi = (int*)((char*)d_ws + FLOAT_END * sizeof(float));

  const bool pre = (ws_size >= RAD_REQ_BYTES);

  hipMemsetAsync(wsi, 0, (size_t)IOFF_NORD * sizeof(int), stream);
  k_prep<<<6876, 256, 0, stream>>>(node_s, node_v, Wu0, Wu1,
                                   remb, radW, radb, ln_g, ln_b,
                                   recv, nspec, pre ? 1 : 0, wsf, wsi);
  k_mid<<<2, 256, 0, stream>>>(wsf, wsi);
  k_fillg<<<690, 256, 0, stream>>>(recv, nspec, stab,
                                   w30e, w31o, w20e, w21o, w10e, w11o,
                                   wsf, wsi);
  if (pre) {
    k_main<1><<<10000, 256, 0, stream>>>(node_s, node_v, vectors, remb, nspec,
                                         radW, radb, ln_g, ln_b, Wd0, Wd1, Wd2,
                                         P0, P1, Wsk0, Wsk1, Wread, wsf, wsi, out);
  } else {
    k_main<0><<<10000, 256, 0, stream>>>(node_s, node_v, vectors, remb, nspec,
                                         radW, radb, ln_g, ln_b, Wd0, Wd1, Wd2,
                                         P0, P1, Wsk0, Wsk1, Wread, wsf, wsi, out);
  }
}